// Round 3
// baseline (818.116 us; speedup 1.0000x reference)
//
#include <hip/hip_runtime.h>
#include <hip/hip_bf16.h>

#define NN 50000
#define NE 500000

using bf16x8 = __attribute__((ext_vector_type(8))) short;
using f32x4  = __attribute__((ext_vector_type(4))) float;

__device__ __forceinline__ float b2f(unsigned short s) {
  union { unsigned u; float f; } v; v.u = ((unsigned)s) << 16; return v.f;
}
__device__ __forceinline__ unsigned short f2b(float f) {
  __hip_bfloat16 h = __float2bfloat16(f);
  return *reinterpret_cast<unsigned short*>(&h);
}
__device__ __forceinline__ float silu_f(float x) { return x / (1.f + __expf(-x)); }

// ---------------- prep: weight repack f32 -> bf16 (K-major, zero-padded) ----
// W1p[528][288]  <- W_e1(257,514)   (n<514,k<257 else 0)
// W2p[64][544]   <- W_e2(514,64)    (k<514 else 0)
// Wc1p[256][64]  <- W_c1(64,256)
// Wn1p[256][192] <- W_n1(192,256)
// Wn2p[128][256] <- W_n2(256,128)
__global__ void prep_weights(const float* __restrict__ we1,
                             const float* __restrict__ we2,
                             const float* __restrict__ wc1,
                             const float* __restrict__ wn1,
                             const float* __restrict__ wn2,
                             unsigned short* __restrict__ W1p,
                             unsigned short* __restrict__ W2p,
                             unsigned short* __restrict__ Wc1p,
                             unsigned short* __restrict__ Wn1p,
                             unsigned short* __restrict__ Wn2p) {
  int i = blockIdx.x * 256 + threadIdx.x;
  if (i < 152064) {
    int n = i / 288, k = i % 288;
    W1p[i] = (n < 514 && k < 257) ? f2b(we1[k * 514 + n]) : (unsigned short)0;
  } else if (i < 186880) {
    int j = i - 152064; int n = j / 544, k = j % 544;
    W2p[j] = (k < 514) ? f2b(we2[k * 64 + n]) : (unsigned short)0;
  } else if (i < 203264) {
    int j = i - 186880; int n = j / 64, k = j % 64;
    Wc1p[j] = f2b(wc1[k * 256 + n]);
  } else if (i < 252416) {
    int j = i - 203264; int n = j / 192, k = j % 192;
    Wn1p[j] = f2b(wn1[k * 256 + n]);
  } else if (i < 285184) {
    int j = i - 252416; int n = j / 256, k = j % 256;
    Wn2p[j] = f2b(wn2[k * 128 + n]);
  }
}

// x(N,131) f32 -> node_p(N,128) bf16 (256B aligned rows) + coords_p(N,4) f32
__global__ void prep_nodes(const float* __restrict__ x,
                           unsigned short* __restrict__ node_p,
                           float* __restrict__ coords_p) {
  int i = blockIdx.x * 256 + threadIdx.x;
  if (i < NN * 16) {
    int g = i >> 4, c = i & 15;
    const float* s = x + g * 131 + c * 8;
    unsigned short* d = node_p + g * 128 + c * 8;
#pragma unroll
    for (int j = 0; j < 8; j++) d[j] = f2b(s[j]);
  } else if (i < NN * 16 + NN) {
    int g = i - NN * 16;
    float4 c;
    c.x = x[g * 131 + 128];
    c.y = x[g * 131 + 129];
    c.z = x[g * 131 + 130];
    c.w = 0.f;
    *(float4*)(coords_p + g * 4) = c;
  }
}

// ---------------- edge kernel: 32 edges / block ----------------
template <int NT>
__device__ __forceinline__ void l1_group(int t0, int l16, int quad,
                                         const unsigned short* __restrict__ W1p,
                                         const float* __restrict__ be1,
                                         const unsigned short (*sEin)[296],
                                         unsigned short (*sH)[552]) {
  f32x4 acc[NT][2];
#pragma unroll
  for (int j = 0; j < NT; j++)
#pragma unroll
    for (int s = 0; s < 2; s++) acc[j][s] = (f32x4){0.f, 0.f, 0.f, 0.f};
  for (int kb = 0; kb < 9; kb++) {
    bf16x8 afr[2], bfr[NT];
#pragma unroll
    for (int s = 0; s < 2; s++)
      afr[s] = *(const bf16x8*)(&sEin[s * 16 + l16][kb * 32 + quad * 8]);
#pragma unroll
    for (int j = 0; j < NT; j++)
      bfr[j] = *(const bf16x8*)(W1p + ((t0 + j) * 16 + l16) * 288 + kb * 32 + quad * 8);
#pragma unroll
    for (int j = 0; j < NT; j++)
#pragma unroll
      for (int s = 0; s < 2; s++)
        acc[j][s] = __builtin_amdgcn_mfma_f32_16x16x32_bf16(afr[s], bfr[j], acc[j][s], 0, 0, 0);
  }
#pragma unroll
  for (int j = 0; j < NT; j++) {
    int n = (t0 + j) * 16 + l16;
    float bias = (n < 514) ? be1[n] : 0.f;
#pragma unroll
    for (int s = 0; s < 2; s++)
#pragma unroll
      for (int r = 0; r < 4; r++)
        sH[s * 16 + quad * 4 + r][n] = f2b(silu_f(acc[j][s][r] + bias));
  }
}

__launch_bounds__(256, 2)
__global__ void edge_kernel(const unsigned short* __restrict__ node_p,
                            const float* __restrict__ coords_p,
                            const int* __restrict__ eidx,
                            const unsigned short* __restrict__ W1p,
                            const unsigned short* __restrict__ W2p,
                            const unsigned short* __restrict__ Wc1p,
                            const float* __restrict__ be1,
                            const float* __restrict__ be2,
                            const float* __restrict__ bc1,
                            const float* __restrict__ bc2,
                            const float* __restrict__ wc2,
                            float* __restrict__ m_i,
                            float* __restrict__ r_i,
                            float* __restrict__ w_i) {
  __shared__ unsigned short sEin[32][296];   // 18,944 B  (K pad 288->296 bank-safe)
  __shared__ unsigned short sH[32][552];     // 35,328 B  (K2 pad 544->552)
  __shared__ unsigned short sM[32][72];      //  4,608 B
  __shared__ int sDst[32];
  __shared__ int sSrc[32];
  __shared__ float sCwPart[4][32];
  int tid = threadIdx.x, blk = blockIdx.x;
  int lane = tid & 63, wv = tid >> 6, l16 = lane & 15, quad = lane >> 4;

  // ---- phase 0: per-edge scalars + r_i atomics + pad zeroing ----
  if (tid < 32) {
    int e = blk * 32 + tid;
    int s = eidx[e], d = eidx[NE + e];
    s = min(max(s, 0), NN - 1);
    d = min(max(d, 0), NN - 1);
    float4 cs = *(const float4*)(coords_p + s * 4);
    float4 cd = *(const float4*)(coords_p + d * 4);
    float rx = cs.x - cd.x, ry = cs.y - cd.y, rz = cs.z - cd.z;
    float dist = sqrtf(rx * rx + ry * ry + rz * rz);
    sDst[tid] = d;
    sSrc[tid] = s;
    sEin[tid][256] = f2b(dist);
#pragma unroll
    for (int k = 257; k < 288; k++) sEin[tid][k] = 0;
    unsafeAtomicAdd(&r_i[d * 4 + 0], rx);
    unsafeAtomicAdd(&r_i[d * 4 + 1], ry);
    unsafeAtomicAdd(&r_i[d * 4 + 2], rz);
  }
  {  // zero sH k-pad cols 528..543 (layer-2 A operand must be finite)
    int r = tid >> 3, c = (tid & 7) * 2;
    sH[r][528 + c] = 0;
    sH[r][528 + c + 1] = 0;
  }
  __syncthreads();
  // ---- gather node features: e_in = [node[dst] | node[src] | dist] ----
#pragma unroll
  for (int it = 0; it < 4; it++) {
    int c = tid + it * 256;
    int row = c >> 5, h = (c >> 4) & 1, off = c & 15;
    int id = h ? sSrc[row] : sDst[row];
    bf16x8 v = *(const bf16x8*)(node_p + id * 128 + off * 8);
    *(bf16x8*)(&sEin[row][h * 128 + off * 8]) = v;
  }
  __syncthreads();

  // ---- layer 1: h = silu(e_in @ W_e1 + b_e1), N-tiles split across waves ----
  l1_group<4>(wv * 4, l16, quad, W1p, be1, sEin, sH);
  l1_group<4>(16 + wv * 4, l16, quad, W1p, be1, sEin, sH);
  if (wv == 0) l1_group<1>(32, l16, quad, W1p, be1, sEin, sH);
  __syncthreads();

  // ---- layer 2: m_ij = silu(h @ W_e2 + b_e2); atomic into m_i[dst] ----
  {
    f32x4 macc[2];
    macc[0] = (f32x4){0.f, 0.f, 0.f, 0.f};
    macc[1] = (f32x4){0.f, 0.f, 0.f, 0.f};
    for (int kb = 0; kb < 17; kb++) {
      bf16x8 b = *(const bf16x8*)(W2p + (wv * 16 + l16) * 544 + kb * 32 + quad * 8);
#pragma unroll
      for (int s = 0; s < 2; s++) {
        bf16x8 a = *(const bf16x8*)(&sH[s * 16 + l16][kb * 32 + quad * 8]);
        macc[s] = __builtin_amdgcn_mfma_f32_16x16x32_bf16(a, b, macc[s], 0, 0, 0);
      }
    }
    int n = wv * 16 + l16;
    float bias = be2[n];
#pragma unroll
    for (int s = 0; s < 2; s++)
#pragma unroll
      for (int r = 0; r < 4; r++) {
        int row = s * 16 + quad * 4 + r;
        float mm = silu_f(macc[s][r] + bias);
        sM[row][n] = f2b(mm);
        unsafeAtomicAdd(&m_i[sDst[row] * 64 + n], mm);
      }
  }
  __syncthreads();

  // ---- coord head: cw = silu(m @ W_c1 + b_c1) @ W_c2 + b_c2 ----
  {
    float cw[2][4] = {{0.f, 0.f, 0.f, 0.f}, {0.f, 0.f, 0.f, 0.f}};
#pragma unroll
    for (int jt = 0; jt < 4; jt++) {
      int T = wv * 4 + jt;
      f32x4 cacc[2];
      cacc[0] = (f32x4){0.f, 0.f, 0.f, 0.f};
      cacc[1] = (f32x4){0.f, 0.f, 0.f, 0.f};
#pragma unroll
      for (int kb = 0; kb < 2; kb++) {
        bf16x8 b = *(const bf16x8*)(Wc1p + (T * 16 + l16) * 64 + kb * 32 + quad * 8);
#pragma unroll
        for (int s = 0; s < 2; s++) {
          bf16x8 a = *(const bf16x8*)(&sM[s * 16 + l16][kb * 32 + quad * 8]);
          cacc[s] = __builtin_amdgcn_mfma_f32_16x16x32_bf16(a, b, cacc[s], 0, 0, 0);
        }
      }
      int n = T * 16 + l16;
      float bias = bc1[n];
      float w2v = wc2[n];
#pragma unroll
      for (int s = 0; s < 2; s++)
#pragma unroll
        for (int r = 0; r < 4; r++)
          cw[s][r] += silu_f(cacc[s][r] + bias) * w2v;
    }
#pragma unroll
    for (int off = 1; off < 16; off <<= 1)
#pragma unroll
      for (int s = 0; s < 2; s++)
#pragma unroll
        for (int r = 0; r < 4; r++)
          cw[s][r] += __shfl_xor(cw[s][r], off, 64);
    if (l16 == 0) {
#pragma unroll
      for (int s = 0; s < 2; s++)
#pragma unroll
        for (int r = 0; r < 4; r++)
          sCwPart[wv][s * 16 + quad * 4 + r] = cw[s][r];
    }
  }
  __syncthreads();
  if (tid < 32) {
    float v = sCwPart[0][tid] + sCwPart[1][tid] + sCwPart[2][tid] + sCwPart[3][tid]
              + bc2[0];
    unsafeAtomicAdd(&w_i[sDst[tid]], v);
  }
}

// ---------------- node kernel: 64 nodes / block, f32 output ----------------
__launch_bounds__(256, 2)
__global__ void node_kernel(const unsigned short* __restrict__ node_p,
                            const float* __restrict__ x,
                            const float* __restrict__ coords_p,
                            const float* __restrict__ m_i,
                            const float* __restrict__ r_i,
                            const float* __restrict__ w_i,
                            const unsigned short* __restrict__ Wn1p,
                            const unsigned short* __restrict__ Wn2p,
                            const float* __restrict__ bn1,
                            const float* __restrict__ bn2,
                            float* __restrict__ out) {
  __shared__ unsigned short sNin[64][200];   // 25,600 B
  __shared__ unsigned short sHid[64][264];   // 33,792 B
  int tid = threadIdx.x, blk = blockIdx.x;
  int lane = tid & 63, wv = tid >> 6, l16 = lane & 15, quad = lane >> 4;

  // stage n_in = [node | bf16(m_i)]
#pragma unroll
  for (int it = 0; it < 8; it++) {
    int c = tid + it * 256;
    int row = c >> 5, cc = c & 31;
    int g = blk * 64 + row;
    if (g >= NN) g = 0;
    if (cc < 16) {
      bf16x8 v = *(const bf16x8*)(node_p + g * 128 + cc * 8);
      *(bf16x8*)(&sNin[row][cc * 8]) = v;
    } else {
      int q = cc - 16;
      float4 v = *(const float4*)(m_i + g * 64 + q * 4);
      unsigned short* p = &sNin[row][128 + q * 4];
      p[0] = f2b(v.x); p[1] = f2b(v.y); p[2] = f2b(v.z); p[3] = f2b(v.w);
    }
  }
  __syncthreads();
  // GEMM1: hid = silu(n_in @ W_n1 + b_n1); wave wv -> tiles 4wv..4wv+3
  {
    f32x4 acc[4][4];
#pragma unroll
    for (int j = 0; j < 4; j++)
#pragma unroll
      for (int s = 0; s < 4; s++) acc[j][s] = (f32x4){0.f, 0.f, 0.f, 0.f};
    for (int kb = 0; kb < 6; kb++) {
      bf16x8 afr[4], bfr[4];
#pragma unroll
      for (int s = 0; s < 4; s++)
        afr[s] = *(const bf16x8*)(&sNin[s * 16 + l16][kb * 32 + quad * 8]);
#pragma unroll
      for (int j = 0; j < 4; j++)
        bfr[j] = *(const bf16x8*)(Wn1p + ((wv * 4 + j) * 16 + l16) * 192 + kb * 32 + quad * 8);
#pragma unroll
      for (int j = 0; j < 4; j++)
#pragma unroll
        for (int s = 0; s < 4; s++)
          acc[j][s] = __builtin_amdgcn_mfma_f32_16x16x32_bf16(afr[s], bfr[j], acc[j][s], 0, 0, 0);
    }
#pragma unroll
    for (int j = 0; j < 4; j++) {
      int n = (wv * 4 + j) * 16 + l16;
      float bias = bn1[n];
#pragma unroll
      for (int s = 0; s < 4; s++)
#pragma unroll
        for (int r = 0; r < 4; r++)
          sHid[s * 16 + quad * 4 + r][n] = f2b(silu_f(acc[j][s][r] + bias));
    }
  }
  __syncthreads();
  // GEMM2: out = hid @ W_n2 + b_n2 + node; wave wv -> tiles 2wv, 2wv+1
  {
    f32x4 acc[2][4];
#pragma unroll
    for (int j = 0; j < 2; j++)
#pragma unroll
      for (int s = 0; s < 4; s++) acc[j][s] = (f32x4){0.f, 0.f, 0.f, 0.f};
    for (int kb = 0; kb < 8; kb++) {
      bf16x8 afr[4], bfr[2];
#pragma unroll
      for (int s = 0; s < 4; s++)
        afr[s] = *(const bf16x8*)(&sHid[s * 16 + l16][kb * 32 + quad * 8]);
#pragma unroll
      for (int j = 0; j < 2; j++)
        bfr[j] = *(const bf16x8*)(Wn2p + ((wv * 2 + j) * 16 + l16) * 256 + kb * 32 + quad * 8);
#pragma unroll
      for (int j = 0; j < 2; j++)
#pragma unroll
        for (int s = 0; s < 4; s++)
          acc[j][s] = __builtin_amdgcn_mfma_f32_16x16x32_bf16(afr[s], bfr[j], acc[j][s], 0, 0, 0);
    }
#pragma unroll
    for (int j = 0; j < 2; j++) {
      int n = (wv * 2 + j) * 16 + l16;
      float bias = bn2[n];
#pragma unroll
      for (int s = 0; s < 4; s++)
#pragma unroll
        for (int r = 0; r < 4; r++) {
          int row = s * 16 + quad * 4 + r;
          int g = blk * 64 + row;
          if (g < NN)
            out[g * 131 + n] = acc[j][s][r] + bias + x[g * 131 + n];
        }
    }
  }
  // coords_out = coords + w_i * r_i
  if (tid < 64) {
    int g = blk * 64 + tid;
    if (g < NN) {
      float wvv = w_i[g];
      float4 rr = *(const float4*)(r_i + g * 4);
      float4 cc = *(const float4*)(coords_p + g * 4);
      out[g * 131 + 128] = cc.x + wvv * rr.x;
      out[g * 131 + 129] = cc.y + wvv * rr.y;
      out[g * 131 + 130] = cc.z + wvv * rr.z;
    }
  }
}

extern "C" void kernel_launch(void* const* d_in, const int* in_sizes, int n_in,
                              void* d_out, int out_size, void* d_ws, size_t ws_size,
                              hipStream_t stream) {
  const float* x   = (const float*)d_in[0];
  const int* eidx  = (const int*)d_in[1];
  const float* we1 = (const float*)d_in[2];
  const float* be1 = (const float*)d_in[3];
  const float* we2 = (const float*)d_in[4];
  const float* be2 = (const float*)d_in[5];
  const float* wc1 = (const float*)d_in[6];
  const float* bc1 = (const float*)d_in[7];
  const float* wc2 = (const float*)d_in[8];
  const float* bc2 = (const float*)d_in[9];
  const float* wn1 = (const float*)d_in[10];
  const float* bn1 = (const float*)d_in[11];
  const float* wn2 = (const float*)d_in[12];
  const float* bn2 = (const float*)d_in[13];

  char* ws = (char*)d_ws;
  unsigned short* W1p    = (unsigned short*)(ws + 0);         // 304,128 B
  unsigned short* W2p    = (unsigned short*)(ws + 304128);    //  69,632 B
  unsigned short* Wc1p   = (unsigned short*)(ws + 373760);    //  32,768 B
  unsigned short* Wn1p   = (unsigned short*)(ws + 406528);    //  98,304 B
  unsigned short* Wn2p   = (unsigned short*)(ws + 504832);    //  65,536 B
  unsigned short* node_p = (unsigned short*)(ws + 570368);    // 12,800,000 B
  float* coords_p        = (float*)(ws + 13370368);           //    800,000 B
  float* m_i             = (float*)(ws + 14170368);           // 12,800,000 B
  float* r_i             = (float*)(ws + 26970368);           //    800,000 B
  float* w_i             = (float*)(ws + 27770368);           //    200,000 B

  hipMemsetAsync(ws + 14170368, 0, 13800000, stream);  // zero m_i | r_i | w_i
  prep_weights<<<(285184 + 255) / 256, 256, 0, stream>>>(we1, we2, wc1, wn1, wn2,
                                                         W1p, W2p, Wc1p, Wn1p, Wn2p);
  prep_nodes<<<(NN * 17 + 255) / 256, 256, 0, stream>>>(x, node_p, coords_p);
  edge_kernel<<<NE / 32, 256, 0, stream>>>(node_p, coords_p, eidx, W1p, W2p, Wc1p,
                                           be1, be2, bc1, bc2, wc2, m_i, r_i, w_i);
  node_kernel<<<(NN + 63) / 64, 256, 0, stream>>>(node_p, x, coords_p, m_i, r_i, w_i,
                                                  Wn1p, Wn2p, bn1, bn2,
                                                  (float*)d_out);
}

// Round 4
// 817.447 us; speedup vs baseline: 1.0008x; 1.0008x over previous
//
#include <hip/hip_runtime.h>
#include <hip/hip_bf16.h>

#define NN 50000
#define NE 500000
#define DCAP 48

using bf16x8 = __attribute__((ext_vector_type(8))) short;
using f32x4  = __attribute__((ext_vector_type(4))) float;

__device__ __forceinline__ float b2f(unsigned short s) {
  union { unsigned u; float f; } v; v.u = ((unsigned)s) << 16; return v.f;
}
__device__ __forceinline__ unsigned short f2b(float f) {
  __hip_bfloat16 h = __float2bfloat16(f);
  return *reinterpret_cast<unsigned short*>(&h);
}
__device__ __forceinline__ float silu_f(float x) { return x / (1.f + __expf(-x)); }

// ---------------- prep: weight repack f32 -> bf16 (K-major, zero-padded) ----
__global__ void prep_weights(const float* __restrict__ we1,
                             const float* __restrict__ we2,
                             const float* __restrict__ wc1,
                             const float* __restrict__ wn1,
                             const float* __restrict__ wn2,
                             unsigned short* __restrict__ W1p,
                             unsigned short* __restrict__ W2p,
                             unsigned short* __restrict__ Wc1p,
                             unsigned short* __restrict__ Wn1p,
                             unsigned short* __restrict__ Wn2p) {
  int i = blockIdx.x * 256 + threadIdx.x;
  if (i < 152064) {
    int n = i / 288, k = i % 288;
    W1p[i] = (n < 514 && k < 257) ? f2b(we1[k * 514 + n]) : (unsigned short)0;
  } else if (i < 186880) {
    int j = i - 152064; int n = j / 544, k = j % 544;
    W2p[j] = (k < 514) ? f2b(we2[k * 64 + n]) : (unsigned short)0;
  } else if (i < 203264) {
    int j = i - 186880; int n = j / 64, k = j % 64;
    Wc1p[j] = f2b(wc1[k * 256 + n]);
  } else if (i < 252416) {
    int j = i - 203264; int n = j / 192, k = j % 192;
    Wn1p[j] = f2b(wn1[k * 256 + n]);
  } else if (i < 285184) {
    int j = i - 252416; int n = j / 256, k = j % 256;
    Wn2p[j] = f2b(wn2[k * 128 + n]);
  }
}

// x(N,131) f32 -> node_p(N,128) bf16 + coords_p(N,4) f32
__global__ void prep_nodes(const float* __restrict__ x,
                           unsigned short* __restrict__ node_p,
                           float* __restrict__ coords_p) {
  int i = blockIdx.x * 256 + threadIdx.x;
  if (i < NN * 16) {
    int g = i >> 4, c = i & 15;
    const float* s = x + g * 131 + c * 8;
    unsigned short* d = node_p + g * 128 + c * 8;
#pragma unroll
    for (int j = 0; j < 8; j++) d[j] = f2b(s[j]);
  } else if (i < NN * 16 + NN) {
    int g = i - NN * 16;
    float4 c;
    c.x = x[g * 131 + 128];
    c.y = x[g * 131 + 129];
    c.z = x[g * 131 + 130];
    c.w = 0.f;
    *(float4*)(coords_p + g * 4) = c;
  }
}

// CSR-lite: per-dst edge list (cap DCAP; Binom(500k,1/50k) max deg ~26)
__global__ void build_adj(const int* __restrict__ eidx,
                          int* __restrict__ cnt, int* __restrict__ adj) {
  int e = blockIdx.x * 256 + threadIdx.x;
  if (e < NE) {
    int d = eidx[NE + e];
    d = min(max(d, 0), NN - 1);
    int slot = atomicAdd(&cnt[d], 1);
    if (slot < DCAP) adj[d * DCAP + slot] = e;
  }
}

// ---------------- edge kernel: 32 edges / block, NO f32 atomics ------------
template <int NT>
__device__ __forceinline__ void l1_group(int t0, int l16, int quad,
                                         const unsigned short* __restrict__ W1p,
                                         const float* __restrict__ be1,
                                         const unsigned short (*sEin)[296],
                                         unsigned short (*sH)[552]) {
  f32x4 acc[NT][2];
#pragma unroll
  for (int j = 0; j < NT; j++)
#pragma unroll
    for (int s = 0; s < 2; s++) acc[j][s] = (f32x4){0.f, 0.f, 0.f, 0.f};
  for (int kb = 0; kb < 9; kb++) {
    bf16x8 afr[2], bfr[NT];
#pragma unroll
    for (int s = 0; s < 2; s++)
      afr[s] = *(const bf16x8*)(&sEin[s * 16 + l16][kb * 32 + quad * 8]);
#pragma unroll
    for (int j = 0; j < NT; j++)
      bfr[j] = *(const bf16x8*)(W1p + ((t0 + j) * 16 + l16) * 288 + kb * 32 + quad * 8);
#pragma unroll
    for (int j = 0; j < NT; j++)
#pragma unroll
      for (int s = 0; s < 2; s++)
        acc[j][s] = __builtin_amdgcn_mfma_f32_16x16x32_bf16(afr[s], bfr[j], acc[j][s], 0, 0, 0);
  }
#pragma unroll
  for (int j = 0; j < NT; j++) {
    int n = (t0 + j) * 16 + l16;
    float bias = (n < 514) ? be1[n] : 0.f;
#pragma unroll
    for (int s = 0; s < 2; s++)
#pragma unroll
      for (int r = 0; r < 4; r++)
        sH[s * 16 + quad * 4 + r][n] = f2b(silu_f(acc[j][s][r] + bias));
  }
}

__launch_bounds__(256, 2)
__global__ void edge_kernel(const unsigned short* __restrict__ node_p,
                            const float* __restrict__ coords_p,
                            const int* __restrict__ eidx,
                            const unsigned short* __restrict__ W1p,
                            const unsigned short* __restrict__ W2p,
                            const unsigned short* __restrict__ Wc1p,
                            const float* __restrict__ be1,
                            const float* __restrict__ be2,
                            const float* __restrict__ bc1,
                            const float* __restrict__ bc2,
                            const float* __restrict__ wc2,
                            unsigned short* __restrict__ medge,
                            float* __restrict__ coordw) {
  __shared__ unsigned short sEin[32][296];
  __shared__ unsigned short sH[32][552];
  __shared__ unsigned short sM[32][72];
  __shared__ int sDst[32];
  __shared__ int sSrc[32];
  __shared__ float sCwPart[4][32];
  int tid = threadIdx.x, blk = blockIdx.x;
  int lane = tid & 63, wv = tid >> 6, l16 = lane & 15, quad = lane >> 4;

  // ---- phase 0: per-edge scalars + pad zeroing ----
  if (tid < 32) {
    int e = blk * 32 + tid;
    int s = eidx[e], d = eidx[NE + e];
    s = min(max(s, 0), NN - 1);
    d = min(max(d, 0), NN - 1);
    float4 cs = *(const float4*)(coords_p + s * 4);
    float4 cd = *(const float4*)(coords_p + d * 4);
    float rx = cs.x - cd.x, ry = cs.y - cd.y, rz = cs.z - cd.z;
    float dist = sqrtf(rx * rx + ry * ry + rz * rz);
    sDst[tid] = d;
    sSrc[tid] = s;
    sEin[tid][256] = f2b(dist);
#pragma unroll
    for (int k = 257; k < 288; k++) sEin[tid][k] = 0;
  }
  {  // zero sH k-pad cols 528..543
    int r = tid >> 3, c = (tid & 7) * 2;
    sH[r][528 + c] = 0;
    sH[r][528 + c + 1] = 0;
  }
  __syncthreads();
  // ---- gather node features: e_in = [node[dst] | node[src] | dist] ----
#pragma unroll
  for (int it = 0; it < 4; it++) {
    int c = tid + it * 256;
    int row = c >> 5, h = (c >> 4) & 1, off = c & 15;
    int id = h ? sSrc[row] : sDst[row];
    bf16x8 v = *(const bf16x8*)(node_p + id * 128 + off * 8);
    *(bf16x8*)(&sEin[row][h * 128 + off * 8]) = v;
  }
  __syncthreads();

  // ---- layer 1 ----
  l1_group<4>(wv * 4, l16, quad, W1p, be1, sEin, sH);
  l1_group<4>(16 + wv * 4, l16, quad, W1p, be1, sEin, sH);
  if (wv == 0) l1_group<1>(32, l16, quad, W1p, be1, sEin, sH);
  __syncthreads();

  // ---- layer 2: m_ij = silu(h @ W_e2 + b_e2) -> sM ----
  {
    f32x4 macc[2];
    macc[0] = (f32x4){0.f, 0.f, 0.f, 0.f};
    macc[1] = (f32x4){0.f, 0.f, 0.f, 0.f};
    for (int kb = 0; kb < 17; kb++) {
      bf16x8 b = *(const bf16x8*)(W2p + (wv * 16 + l16) * 544 + kb * 32 + quad * 8);
#pragma unroll
      for (int s = 0; s < 2; s++) {
        bf16x8 a = *(const bf16x8*)(&sH[s * 16 + l16][kb * 32 + quad * 8]);
        macc[s] = __builtin_amdgcn_mfma_f32_16x16x32_bf16(a, b, macc[s], 0, 0, 0);
      }
    }
    int n = wv * 16 + l16;
    float bias = be2[n];
#pragma unroll
    for (int s = 0; s < 2; s++)
#pragma unroll
      for (int r = 0; r < 4; r++) {
        int row = s * 16 + quad * 4 + r;
        sM[row][n] = f2b(silu_f(macc[s][r] + bias));
      }
  }
  __syncthreads();

  // ---- coord head: cw = silu(m @ W_c1 + b_c1) @ W_c2 ----
  {
    float cw[2][4] = {{0.f, 0.f, 0.f, 0.f}, {0.f, 0.f, 0.f, 0.f}};
#pragma unroll
    for (int jt = 0; jt < 4; jt++) {
      int T = wv * 4 + jt;
      f32x4 cacc[2];
      cacc[0] = (f32x4){0.f, 0.f, 0.f, 0.f};
      cacc[1] = (f32x4){0.f, 0.f, 0.f, 0.f};
#pragma unroll
      for (int kb = 0; kb < 2; kb++) {
        bf16x8 b = *(const bf16x8*)(Wc1p + (T * 16 + l16) * 64 + kb * 32 + quad * 8);
#pragma unroll
        for (int s = 0; s < 2; s++) {
          bf16x8 a = *(const bf16x8*)(&sM[s * 16 + l16][kb * 32 + quad * 8]);
          cacc[s] = __builtin_amdgcn_mfma_f32_16x16x32_bf16(a, b, cacc[s], 0, 0, 0);
        }
      }
      int n = T * 16 + l16;
      float bias = bc1[n];
      float w2v = wc2[n];
#pragma unroll
      for (int s = 0; s < 2; s++)
#pragma unroll
        for (int r = 0; r < 4; r++)
          cw[s][r] += silu_f(cacc[s][r] + bias) * w2v;
    }
#pragma unroll
    for (int off = 1; off < 16; off <<= 1)
#pragma unroll
      for (int s = 0; s < 2; s++)
#pragma unroll
        for (int r = 0; r < 4; r++)
          cw[s][r] += __shfl_xor(cw[s][r], off, 64);
    if (l16 == 0) {
#pragma unroll
      for (int s = 0; s < 2; s++)
#pragma unroll
        for (int r = 0; r < 4; r++)
          sCwPart[wv][s * 16 + quad * 4 + r] = cw[s][r];
    }
  }
  __syncthreads();
  // ---- coalesced stores: m_ij rows (16B/lane) + coord_w scalar ----
  {
    int row = tid >> 3, ch = tid & 7;
    int e = blk * 32 + row;
    *(bf16x8*)(medge + (size_t)e * 64 + ch * 8) = *(const bf16x8*)(&sM[row][ch * 8]);
  }
  if (tid < 32) {
    float v = sCwPart[0][tid] + sCwPart[1][tid] + sCwPart[2][tid] + sCwPart[3][tid]
              + bc2[0];
    coordw[blk * 32 + tid] = v;
  }
}

// ---------------- node kernel: gather-reduce + MLP, f32 output -------------
__launch_bounds__(256, 2)
__global__ void node_kernel(const unsigned short* __restrict__ node_p,
                            const float* __restrict__ x,
                            const float* __restrict__ coords_p,
                            const unsigned short* __restrict__ medge,
                            const float* __restrict__ coordw,
                            const int* __restrict__ eidx,
                            const int* __restrict__ cnt,
                            const int* __restrict__ adj,
                            const unsigned short* __restrict__ Wn1p,
                            const unsigned short* __restrict__ Wn2p,
                            const float* __restrict__ bn1,
                            const float* __restrict__ bn2,
                            float* __restrict__ out) {
  __shared__ unsigned short sNin[64][200];
  __shared__ unsigned short sHid[64][264];
  __shared__ float sWR[64][4];   // [rx, ry, rz, w] per node
  int tid = threadIdx.x, blk = blockIdx.x;
  int lane = tid & 63, wv = tid >> 6, l16 = lane & 15, quad = lane >> 4;

  // ---- phase A: gather-reduce m_i (f32), r_i, w_i — no atomics ----
  {
    int j = tid >> 2, c = tid & 3;          // 4 lanes per node, 16 cols each
    int g = blk * 64 + j;
    int gc = min(g, NN - 1);
    int deg = min(cnt[gc], DCAP);
    if (g >= NN) deg = 0;
    float acc[16];
#pragma unroll
    for (int i = 0; i < 16; i++) acc[i] = 0.f;
    float sc = 0.f;
    float cg = (c < 3) ? coords_p[gc * 4 + c] : 0.f;
    for (int k = 0; k < deg; k++) {
      int e = adj[gc * DCAP + k];
      const unsigned short* mrow = medge + (size_t)e * 64 + c * 16;
      bf16x8 a0 = *(const bf16x8*)(mrow);
      bf16x8 a1 = *(const bf16x8*)(mrow + 8);
#pragma unroll
      for (int i = 0; i < 8; i++) acc[i] += b2f((unsigned short)a0[i]);
#pragma unroll
      for (int i = 0; i < 8; i++) acc[8 + i] += b2f((unsigned short)a1[i]);
      if (c == 3) {
        sc += coordw[e];
      } else {
        int s = eidx[e];
        s = min(max(s, 0), NN - 1);
        sc += coords_p[s * 4 + c] - cg;
      }
    }
#pragma unroll
    for (int i = 0; i < 16; i++) sNin[j][128 + c * 16 + i] = f2b(acc[i]);
    sWR[j][c] = sc;
  }
  // ---- stage node features ----
#pragma unroll
  for (int it = 0; it < 4; it++) {
    int t = tid + it * 256;
    int row = t >> 4, ch = t & 15;
    int g = blk * 64 + row;
    if (g >= NN) g = 0;
    *(bf16x8*)(&sNin[row][ch * 8]) = *(const bf16x8*)(node_p + g * 128 + ch * 8);
  }
  __syncthreads();
  // ---- GEMM1: hid = silu(n_in @ W_n1 + b_n1) ----
  {
    f32x4 acc[4][4];
#pragma unroll
    for (int j = 0; j < 4; j++)
#pragma unroll
      for (int s = 0; s < 4; s++) acc[j][s] = (f32x4){0.f, 0.f, 0.f, 0.f};
    for (int kb = 0; kb < 6; kb++) {
      bf16x8 afr[4], bfr[4];
#pragma unroll
      for (int s = 0; s < 4; s++)
        afr[s] = *(const bf16x8*)(&sNin[s * 16 + l16][kb * 32 + quad * 8]);
#pragma unroll
      for (int j = 0; j < 4; j++)
        bfr[j] = *(const bf16x8*)(Wn1p + ((wv * 4 + j) * 16 + l16) * 192 + kb * 32 + quad * 8);
#pragma unroll
      for (int j = 0; j < 4; j++)
#pragma unroll
        for (int s = 0; s < 4; s++)
          acc[j][s] = __builtin_amdgcn_mfma_f32_16x16x32_bf16(afr[s], bfr[j], acc[j][s], 0, 0, 0);
    }
#pragma unroll
    for (int j = 0; j < 4; j++) {
      int n = (wv * 4 + j) * 16 + l16;
      float bias = bn1[n];
#pragma unroll
      for (int s = 0; s < 4; s++)
#pragma unroll
        for (int r = 0; r < 4; r++)
          sHid[s * 16 + quad * 4 + r][n] = f2b(silu_f(acc[j][s][r] + bias));
    }
  }
  __syncthreads();
  // ---- GEMM2: out = hid @ W_n2 + b_n2 + node (f32 residual from x) ----
  {
    f32x4 acc[2][4];
#pragma unroll
    for (int j = 0; j < 2; j++)
#pragma unroll
      for (int s = 0; s < 4; s++) acc[j][s] = (f32x4){0.f, 0.f, 0.f, 0.f};
    for (int kb = 0; kb < 8; kb++) {
      bf16x8 afr[4], bfr[2];
#pragma unroll
      for (int s = 0; s < 4; s++)
        afr[s] = *(const bf16x8*)(&sHid[s * 16 + l16][kb * 32 + quad * 8]);
#pragma unroll
      for (int j = 0; j < 2; j++)
        bfr[j] = *(const bf16x8*)(Wn2p + ((wv * 2 + j) * 16 + l16) * 256 + kb * 32 + quad * 8);
#pragma unroll
      for (int j = 0; j < 2; j++)
#pragma unroll
        for (int s = 0; s < 4; s++)
          acc[j][s] = __builtin_amdgcn_mfma_f32_16x16x32_bf16(afr[s], bfr[j], acc[j][s], 0, 0, 0);
    }
#pragma unroll
    for (int j = 0; j < 2; j++) {
      int n = (wv * 2 + j) * 16 + l16;
      float bias = bn2[n];
#pragma unroll
      for (int s = 0; s < 4; s++)
#pragma unroll
        for (int r = 0; r < 4; r++) {
          int row = s * 16 + quad * 4 + r;
          int g = blk * 64 + row;
          if (g < NN)
            out[g * 131 + n] = acc[j][s][r] + bias + x[g * 131 + n];
        }
    }
  }
  // ---- coords_out = coords + w_i * r_i ----
  if (tid < 64) {
    int g = blk * 64 + tid;
    if (g < NN) {
      float w = sWR[tid][3];
      out[g * 131 + 128] = coords_p[g * 4 + 0] + w * sWR[tid][0];
      out[g * 131 + 129] = coords_p[g * 4 + 1] + w * sWR[tid][1];
      out[g * 131 + 130] = coords_p[g * 4 + 2] + w * sWR[tid][2];
    }
  }
}

extern "C" void kernel_launch(void* const* d_in, const int* in_sizes, int n_in,
                              void* d_out, int out_size, void* d_ws, size_t ws_size,
                              hipStream_t stream) {
  const float* x   = (const float*)d_in[0];
  const int* eidx  = (const int*)d_in[1];
  const float* we1 = (const float*)d_in[2];
  const float* be1 = (const float*)d_in[3];
  const float* we2 = (const float*)d_in[4];
  const float* be2 = (const float*)d_in[5];
  const float* wc1 = (const float*)d_in[6];
  const float* bc1 = (const float*)d_in[7];
  const float* wc2 = (const float*)d_in[8];
  const float* bc2 = (const float*)d_in[9];
  const float* wn1 = (const float*)d_in[10];
  const float* bn1 = (const float*)d_in[11];
  const float* wn2 = (const float*)d_in[12];
  const float* bn2 = (const float*)d_in[13];

  char* ws = (char*)d_ws;
  unsigned short* W1p    = (unsigned short*)(ws + 0);          //    304,128 B
  unsigned short* W2p    = (unsigned short*)(ws + 304128);     //     69,632 B
  unsigned short* Wc1p   = (unsigned short*)(ws + 373760);     //     32,768 B
  unsigned short* Wn1p   = (unsigned short*)(ws + 406528);     //     98,304 B
  unsigned short* Wn2p   = (unsigned short*)(ws + 504832);     //     65,536 B
  unsigned short* node_p = (unsigned short*)(ws + 570368);     // 12,800,000 B
  float* coords_p        = (float*)(ws + 13370368);            //    800,000 B
  unsigned short* medge  = (unsigned short*)(ws + 14170368);   // 64,000,000 B
  float* coordw          = (float*)(ws + 78170368);            //  2,000,000 B
  int* cnt               = (int*)(ws + 80170368);              //    200,000 B
  int* adj               = (int*)(ws + 80370368);              //  9,600,000 B

  hipMemsetAsync(cnt, 0, NN * sizeof(int), stream);
  prep_weights<<<(285184 + 255) / 256, 256, 0, stream>>>(we1, we2, wc1, wn1, wn2,
                                                         W1p, W2p, Wc1p, Wn1p, Wn2p);
  prep_nodes<<<(NN * 17 + 255) / 256, 256, 0, stream>>>(x, node_p, coords_p);
  build_adj<<<(NE + 255) / 256, 256, 0, stream>>>(eidx, cnt, adj);
  edge_kernel<<<NE / 32, 256, 0, stream>>>(node_p, coords_p, eidx, W1p, W2p, Wc1p,
                                           be1, be2, bc1, bc2, wc2, medge, coordw);
  node_kernel<<<(NN + 63) / 64, 256, 0, stream>>>(node_p, x, coords_p, medge, coordw,
                                                  eidx, cnt, adj, Wn1p, Wn2p, bn1, bn2,
                                                  (float*)d_out);
}

// Round 5
// 688.240 us; speedup vs baseline: 1.1887x; 1.1877x over previous
//
#include <hip/hip_runtime.h>
#include <hip/hip_bf16.h>

#define NN 50000
#define NE 500000
#define DCAP 48

using bf16x8 = __attribute__((ext_vector_type(8))) short;
using f32x4  = __attribute__((ext_vector_type(4))) float;

__device__ __forceinline__ float b2f(unsigned short s) {
  union { unsigned u; float f; } v; v.u = ((unsigned)s) << 16; return v.f;
}
__device__ __forceinline__ unsigned short f2b(float f) {
  __hip_bfloat16 h = __float2bfloat16(f);
  return *reinterpret_cast<unsigned short*>(&h);
}
// fast silu: v_exp + v_rcp (no div refinement) — error ~1ulp of rcp, fine for bf16
__device__ __forceinline__ float silu_f(float x) {
  return x * __fdividef(1.f, 1.f + __expf(-x));
}

// ---------------- prep: weight repack f32 -> bf16 (K-major, zero-padded) ----
__global__ void prep_weights(const float* __restrict__ we1,
                             const float* __restrict__ we2,
                             const float* __restrict__ wc1,
                             const float* __restrict__ wn1,
                             const float* __restrict__ wn2,
                             unsigned short* __restrict__ W1p,
                             unsigned short* __restrict__ W2p,
                             unsigned short* __restrict__ Wc1p,
                             unsigned short* __restrict__ Wn1p,
                             unsigned short* __restrict__ Wn2p) {
  int i = blockIdx.x * 256 + threadIdx.x;
  if (i < 152064) {
    int n = i / 288, k = i % 288;
    W1p[i] = (n < 514 && k < 257) ? f2b(we1[k * 514 + n]) : (unsigned short)0;
  } else if (i < 186880) {
    int j = i - 152064; int n = j / 544, k = j % 544;
    W2p[j] = (k < 514) ? f2b(we2[k * 64 + n]) : (unsigned short)0;
  } else if (i < 203264) {
    int j = i - 186880; int n = j / 64, k = j % 64;
    Wc1p[j] = f2b(wc1[k * 256 + n]);
  } else if (i < 252416) {
    int j = i - 203264; int n = j / 192, k = j % 192;
    Wn1p[j] = f2b(wn1[k * 256 + n]);
  } else if (i < 285184) {
    int j = i - 252416; int n = j / 256, k = j % 256;
    Wn2p[j] = f2b(wn2[k * 128 + n]);
  }
}

// x(N,131) f32 -> node_p(N,128) bf16 + coords_p(N,4) f32
__global__ void prep_nodes(const float* __restrict__ x,
                           unsigned short* __restrict__ node_p,
                           float* __restrict__ coords_p) {
  int i = blockIdx.x * 256 + threadIdx.x;
  if (i < NN * 16) {
    int g = i >> 4, c = i & 15;
    const float* s = x + g * 131 + c * 8;
    unsigned short* d = node_p + g * 128 + c * 8;
#pragma unroll
    for (int j = 0; j < 8; j++) d[j] = f2b(s[j]);
  } else if (i < NN * 16 + NN) {
    int g = i - NN * 16;
    float4 c;
    c.x = x[g * 131 + 128];
    c.y = x[g * 131 + 129];
    c.z = x[g * 131 + 130];
    c.w = 0.f;
    *(float4*)(coords_p + g * 4) = c;
  }
}

// CSR-lite: per-dst edge list (cap DCAP; Binom(500k,1/50k) max deg ~26)
__global__ void build_adj(const int* __restrict__ eidx,
                          int* __restrict__ cnt, int* __restrict__ adj) {
  int e = blockIdx.x * 256 + threadIdx.x;
  if (e < NE) {
    int d = eidx[NE + e];
    d = min(max(d, 0), NN - 1);
    int slot = atomicAdd(&cnt[d], 1);
    if (slot < DCAP) adj[d * DCAP + slot] = e;
  }
}

// ------------- edge kernel: 32 edges / block, chunked L2-fusion -------------
// LDS 33.0 KB -> 4 blocks/CU (16 waves). Layer-1 h produced in 128-col chunks
// into sHc; layer-2 K-partial accumulated immediately; sHc reused (2-barrier
// chunk loop). No f32 atomics anywhere.
__launch_bounds__(256, 4)
__global__ void edge_kernel(const unsigned short* __restrict__ node_p,
                            const float* __restrict__ coords_p,
                            const int* __restrict__ eidx,
                            const unsigned short* __restrict__ W1p,
                            const unsigned short* __restrict__ W2p,
                            const unsigned short* __restrict__ Wc1p,
                            const float* __restrict__ be1,
                            const float* __restrict__ be2,
                            const float* __restrict__ bc1,
                            const float* __restrict__ bc2,
                            const float* __restrict__ wc2,
                            unsigned short* __restrict__ medge,
                            float* __restrict__ coordw) {
  __shared__ unsigned short sEin[32][296];  // 18,944 B
  __shared__ unsigned short sHc[32][136];   //  8,704 B (one 128-col h chunk)
  __shared__ unsigned short sM[32][72];     //  4,608 B
  __shared__ int sDst[32];
  __shared__ int sSrc[32];
  __shared__ float sCwPart[4][32];
  int tid = threadIdx.x, blk = blockIdx.x;
  int lane = tid & 63, wv = tid >> 6, l16 = lane & 15, quad = lane >> 4;

  // ---- phase 0: per-edge scalars ----
  if (tid < 32) {
    int e = blk * 32 + tid;
    int s = eidx[e], d = eidx[NE + e];
    s = min(max(s, 0), NN - 1);
    d = min(max(d, 0), NN - 1);
    float4 cs = *(const float4*)(coords_p + s * 4);
    float4 cd = *(const float4*)(coords_p + d * 4);
    float rx = cs.x - cd.x, ry = cs.y - cd.y, rz = cs.z - cd.z;
    float dist = sqrtf(rx * rx + ry * ry + rz * rz);
    sDst[tid] = d;
    sSrc[tid] = s;
    sEin[tid][256] = f2b(dist);
#pragma unroll
    for (int k = 257; k < 288; k++) sEin[tid][k] = 0;
  }
  __syncthreads();
  // ---- gather node features: e_in = [node[dst] | node[src] | dist] ----
#pragma unroll
  for (int it = 0; it < 4; it++) {
    int c = tid + it * 256;
    int row = c >> 5, h = (c >> 4) & 1, off = c & 15;
    int id = h ? sSrc[row] : sDst[row];
    bf16x8 v = *(const bf16x8*)(node_p + id * 128 + off * 8);
    *(bf16x8*)(&sEin[row][h * 128 + off * 8]) = v;
  }
  __syncthreads();

  // ---- fused layer1+layer2 over 5 K-chunks (4x128 + 1x32 cols of h) ----
  f32x4 macc[2];
  macc[0] = (f32x4){0.f, 0.f, 0.f, 0.f};
  macc[1] = (f32x4){0.f, 0.f, 0.f, 0.f};
#pragma unroll 1
  for (int ch = 0; ch < 5; ch++) {
    if (ch < 4) {
      // produce tiles t = ch*8 + wv*2 + {0,1}  (n = t*16+l16 <= 511 < 514)
      f32x4 acc[2][2];
#pragma unroll
      for (int j = 0; j < 2; j++)
#pragma unroll
        for (int s = 0; s < 2; s++) acc[j][s] = (f32x4){0.f, 0.f, 0.f, 0.f};
      for (int kb = 0; kb < 9; kb++) {
        bf16x8 afr[2], bfr[2];
#pragma unroll
        for (int s = 0; s < 2; s++)
          afr[s] = *(const bf16x8*)(&sEin[s * 16 + l16][kb * 32 + quad * 8]);
#pragma unroll
        for (int j = 0; j < 2; j++)
          bfr[j] = *(const bf16x8*)(W1p + ((ch * 8 + wv * 2 + j) * 16 + l16) * 288 + kb * 32 + quad * 8);
#pragma unroll
        for (int j = 0; j < 2; j++)
#pragma unroll
          for (int s = 0; s < 2; s++)
            acc[j][s] = __builtin_amdgcn_mfma_f32_16x16x32_bf16(afr[s], bfr[j], acc[j][s], 0, 0, 0);
      }
#pragma unroll
      for (int j = 0; j < 2; j++) {
        int n = (ch * 8 + wv * 2 + j) * 16 + l16;
        float bias = be1[n];
        int lc = (wv * 2 + j) * 16 + l16;
#pragma unroll
        for (int s = 0; s < 2; s++)
#pragma unroll
          for (int r = 0; r < 4; r++)
            sHc[s * 16 + quad * 4 + r][lc] = f2b(silu_f(acc[j][s][r] + bias));
      }
    } else {
      if (wv == 0) {  // tile 32: n = 512+l16, mask n<514
        f32x4 acc[2];
        acc[0] = (f32x4){0.f, 0.f, 0.f, 0.f};
        acc[1] = (f32x4){0.f, 0.f, 0.f, 0.f};
        for (int kb = 0; kb < 9; kb++) {
          bf16x8 b = *(const bf16x8*)(W1p + (512 + l16) * 288 + kb * 32 + quad * 8);
#pragma unroll
          for (int s = 0; s < 2; s++) {
            bf16x8 a = *(const bf16x8*)(&sEin[s * 16 + l16][kb * 32 + quad * 8]);
            acc[s] = __builtin_amdgcn_mfma_f32_16x16x32_bf16(a, b, acc[s], 0, 0, 0);
          }
        }
        int n = 512 + l16;
        float bias = (n < 514) ? be1[n] : 0.f;
#pragma unroll
        for (int s = 0; s < 2; s++)
#pragma unroll
          for (int r = 0; r < 4; r++) {
            float v = (n < 514) ? silu_f(acc[s][r] + bias) : 0.f;
            sHc[s * 16 + quad * 4 + r][l16] = f2b(v);
          }
      } else if (wv == 1) {  // zero-fill cols 16..31 (pad tile 33)
#pragma unroll
        for (int s = 0; s < 2; s++)
#pragma unroll
          for (int r = 0; r < 4; r++)
            sHc[s * 16 + quad * 4 + r][16 + l16] = 0;
      }
    }
    __syncthreads();
    // consume: layer2 partial over this chunk's K
    int nkb = (ch < 4) ? 4 : 1;
    for (int kb = 0; kb < nkb; kb++) {
      bf16x8 b = *(const bf16x8*)(W2p + (wv * 16 + l16) * 544 + ch * 128 + kb * 32 + quad * 8);
#pragma unroll
      for (int s = 0; s < 2; s++) {
        bf16x8 a = *(const bf16x8*)(&sHc[s * 16 + l16][kb * 32 + quad * 8]);
        macc[s] = __builtin_amdgcn_mfma_f32_16x16x32_bf16(a, b, macc[s], 0, 0, 0);
      }
    }
    __syncthreads();
  }

  // ---- layer 2 epilogue: m_ij = silu(. + b_e2) -> sM ----
  {
    int n = wv * 16 + l16;
    float bias = be2[n];
#pragma unroll
    for (int s = 0; s < 2; s++)
#pragma unroll
      for (int r = 0; r < 4; r++) {
        int row = s * 16 + quad * 4 + r;
        sM[row][n] = f2b(silu_f(macc[s][r] + bias));
      }
  }
  __syncthreads();

  // ---- coord head: cw = silu(m @ W_c1 + b_c1) @ W_c2 ----
  {
    float cw[2][4] = {{0.f, 0.f, 0.f, 0.f}, {0.f, 0.f, 0.f, 0.f}};
#pragma unroll
    for (int jt = 0; jt < 4; jt++) {
      int T = wv * 4 + jt;
      f32x4 cacc[2];
      cacc[0] = (f32x4){0.f, 0.f, 0.f, 0.f};
      cacc[1] = (f32x4){0.f, 0.f, 0.f, 0.f};
#pragma unroll
      for (int kb = 0; kb < 2; kb++) {
        bf16x8 b = *(const bf16x8*)(Wc1p + (T * 16 + l16) * 64 + kb * 32 + quad * 8);
#pragma unroll
        for (int s = 0; s < 2; s++) {
          bf16x8 a = *(const bf16x8*)(&sM[s * 16 + l16][kb * 32 + quad * 8]);
          cacc[s] = __builtin_amdgcn_mfma_f32_16x16x32_bf16(a, b, cacc[s], 0, 0, 0);
        }
      }
      int n = T * 16 + l16;
      float bias = bc1[n];
      float w2v = wc2[n];
#pragma unroll
      for (int s = 0; s < 2; s++)
#pragma unroll
        for (int r = 0; r < 4; r++)
          cw[s][r] += silu_f(cacc[s][r] + bias) * w2v;
    }
#pragma unroll
    for (int off = 1; off < 16; off <<= 1)
#pragma unroll
      for (int s = 0; s < 2; s++)
#pragma unroll
        for (int r = 0; r < 4; r++)
          cw[s][r] += __shfl_xor(cw[s][r], off, 64);
    if (l16 == 0) {
#pragma unroll
      for (int s = 0; s < 2; s++)
#pragma unroll
        for (int r = 0; r < 4; r++)
          sCwPart[wv][s * 16 + quad * 4 + r] = cw[s][r];
    }
  }
  __syncthreads();
  // ---- coalesced stores: m_ij rows (16B/lane) + coord_w scalar ----
  {
    int row = tid >> 3, ch = tid & 7;
    int e = blk * 32 + row;
    *(bf16x8*)(medge + (size_t)e * 64 + ch * 8) = *(const bf16x8*)(&sM[row][ch * 8]);
  }
  if (tid < 32) {
    float v = sCwPart[0][tid] + sCwPart[1][tid] + sCwPart[2][tid] + sCwPart[3][tid]
              + bc2[0];
    coordw[blk * 32 + tid] = v;
  }
}

// ---------------- node kernel: gather-reduce + MLP, f32 output -------------
__launch_bounds__(256, 2)
__global__ void node_kernel(const unsigned short* __restrict__ node_p,
                            const float* __restrict__ x,
                            const float* __restrict__ coords_p,
                            const unsigned short* __restrict__ medge,
                            const float* __restrict__ coordw,
                            const int* __restrict__ eidx,
                            const int* __restrict__ cnt,
                            const int* __restrict__ adj,
                            const unsigned short* __restrict__ Wn1p,
                            const unsigned short* __restrict__ Wn2p,
                            const float* __restrict__ bn1,
                            const float* __restrict__ bn2,
                            float* __restrict__ out) {
  __shared__ unsigned short sNin[64][200];
  __shared__ unsigned short sHid[64][264];
  __shared__ float sWR[64][4];   // [rx, ry, rz, w] per node
  int tid = threadIdx.x, blk = blockIdx.x;
  int lane = tid & 63, wv = tid >> 6, l16 = lane & 15, quad = lane >> 4;

  // ---- phase A: gather-reduce m_i (f32), r_i, w_i — no atomics ----
  {
    int j = tid >> 2, c = tid & 3;          // 4 lanes per node, 16 cols each
    int g = blk * 64 + j;
    int gc = min(g, NN - 1);
    int deg = min(cnt[gc], DCAP);
    if (g >= NN) deg = 0;
    float acc[16];
#pragma unroll
    for (int i = 0; i < 16; i++) acc[i] = 0.f;
    float sc = 0.f;
    float cg = (c < 3) ? coords_p[gc * 4 + c] : 0.f;
    for (int k = 0; k < deg; k++) {
      int e = adj[gc * DCAP + k];
      const unsigned short* mrow = medge + (size_t)e * 64 + c * 16;
      bf16x8 a0 = *(const bf16x8*)(mrow);
      bf16x8 a1 = *(const bf16x8*)(mrow + 8);
#pragma unroll
      for (int i = 0; i < 8; i++) acc[i] += b2f((unsigned short)a0[i]);
#pragma unroll
      for (int i = 0; i < 8; i++) acc[8 + i] += b2f((unsigned short)a1[i]);
      if (c == 3) {
        sc += coordw[e];
      } else {
        int s = eidx[e];
        s = min(max(s, 0), NN - 1);
        sc += coords_p[s * 4 + c] - cg;
      }
    }
#pragma unroll
    for (int i = 0; i < 16; i++) sNin[j][128 + c * 16 + i] = f2b(acc[i]);
    sWR[j][c] = sc;
  }
  // ---- stage node features ----
#pragma unroll
  for (int it = 0; it < 4; it++) {
    int t = tid + it * 256;
    int row = t >> 4, ch = t & 15;
    int g = blk * 64 + row;
    if (g >= NN) g = 0;
    *(bf16x8*)(&sNin[row][ch * 8]) = *(const bf16x8*)(node_p + g * 128 + ch * 8);
  }
  __syncthreads();
  // ---- GEMM1: hid = silu(n_in @ W_n1 + b_n1) ----
  {
    f32x4 acc[4][4];
#pragma unroll
    for (int j = 0; j < 4; j++)
#pragma unroll
      for (int s = 0; s < 4; s++) acc[j][s] = (f32x4){0.f, 0.f, 0.f, 0.f};
    for (int kb = 0; kb < 6; kb++) {
      bf16x8 afr[4], bfr[4];
#pragma unroll
      for (int s = 0; s < 4; s++)
        afr[s] = *(const bf16x8*)(&sNin[s * 16 + l16][kb * 32 + quad * 8]);
#pragma unroll
      for (int j = 0; j < 4; j++)
        bfr[j] = *(const bf16x8*)(Wn1p + ((wv * 4 + j) * 16 + l16) * 192 + kb * 32 + quad * 8);
#pragma unroll
      for (int j = 0; j < 4; j++)
#pragma unroll
        for (int s = 0; s < 4; s++)
          acc[j][s] = __builtin_amdgcn_mfma_f32_16x16x32_bf16(afr[s], bfr[j], acc[j][s], 0, 0, 0);
    }
#pragma unroll
    for (int j = 0; j < 4; j++) {
      int n = (wv * 4 + j) * 16 + l16;
      float bias = bn1[n];
#pragma unroll
      for (int s = 0; s < 4; s++)
#pragma unroll
        for (int r = 0; r < 4; r++)
          sHid[s * 16 + quad * 4 + r][n] = f2b(silu_f(acc[j][s][r] + bias));
    }
  }
  __syncthreads();
  // ---- GEMM2: out = hid @ W_n2 + b_n2 + node (f32 residual from x) ----
  {
    f32x4 acc[2][4];
#pragma unroll
    for (int j = 0; j < 2; j++)
#pragma unroll
      for (int s = 0; s < 4; s++) acc[j][s] = (f32x4){0.f, 0.f, 0.f, 0.f};
    for (int kb = 0; kb < 8; kb++) {
      bf16x8 afr[4], bfr[2];
#pragma unroll
      for (int s = 0; s < 4; s++)
        afr[s] = *(const bf16x8*)(&sHid[s * 16 + l16][kb * 32 + quad * 8]);
#pragma unroll
      for (int j = 0; j < 2; j++)
        bfr[j] = *(const bf16x8*)(Wn2p + ((wv * 2 + j) * 16 + l16) * 256 + kb * 32 + quad * 8);
#pragma unroll
      for (int j = 0; j < 2; j++)
#pragma unroll
        for (int s = 0; s < 4; s++)
          acc[j][s] = __builtin_amdgcn_mfma_f32_16x16x32_bf16(afr[s], bfr[j], acc[j][s], 0, 0, 0);
    }
#pragma unroll
    for (int j = 0; j < 2; j++) {
      int n = (wv * 2 + j) * 16 + l16;
      float bias = bn2[n];
#pragma unroll
      for (int s = 0; s < 4; s++)
#pragma unroll
        for (int r = 0; r < 4; r++) {
          int row = s * 16 + quad * 4 + r;
          int g = blk * 64 + row;
          if (g < NN)
            out[g * 131 + n] = acc[j][s][r] + bias + x[g * 131 + n];
        }
    }
  }
  // ---- coords_out = coords + w_i * r_i ----
  if (tid < 64) {
    int g = blk * 64 + tid;
    if (g < NN) {
      float w = sWR[tid][3];
      out[g * 131 + 128] = coords_p[g * 4 + 0] + w * sWR[tid][0];
      out[g * 131 + 129] = coords_p[g * 4 + 1] + w * sWR[tid][1];
      out[g * 131 + 130] = coords_p[g * 4 + 2] + w * sWR[tid][2];
    }
  }
}

extern "C" void kernel_launch(void* const* d_in, const int* in_sizes, int n_in,
                              void* d_out, int out_size, void* d_ws, size_t ws_size,
                              hipStream_t stream) {
  const float* x   = (const float*)d_in[0];
  const int* eidx  = (const int*)d_in[1];
  const float* we1 = (const float*)d_in[2];
  const float* be1 = (const float*)d_in[3];
  const float* we2 = (const float*)d_in[4];
  const float* be2 = (const float*)d_in[5];
  const float* wc1 = (const float*)d_in[6];
  const float* bc1 = (const float*)d_in[7];
  const float* wc2 = (const float*)d_in[8];
  const float* bc2 = (const float*)d_in[9];
  const float* wn1 = (const float*)d_in[10];
  const float* bn1 = (const float*)d_in[11];
  const float* wn2 = (const float*)d_in[12];
  const float* bn2 = (const float*)d_in[13];

  char* ws = (char*)d_ws;
  unsigned short* W1p    = (unsigned short*)(ws + 0);          //    304,128 B
  unsigned short* W2p    = (unsigned short*)(ws + 304128);     //     69,632 B
  unsigned short* Wc1p   = (unsigned short*)(ws + 373760);     //     32,768 B
  unsigned short* Wn1p   = (unsigned short*)(ws + 406528);     //     98,304 B
  unsigned short* Wn2p   = (unsigned short*)(ws + 504832);     //     65,536 B
  unsigned short* node_p = (unsigned short*)(ws + 570368);     // 12,800,000 B
  float* coords_p        = (float*)(ws + 13370368);            //    800,000 B
  unsigned short* medge  = (unsigned short*)(ws + 14170368);   // 64,000,000 B
  float* coordw          = (float*)(ws + 78170368);            //  2,000,000 B
  int* cnt               = (int*)(ws + 80170368);              //    200,000 B
  int* adj               = (int*)(ws + 80370368);              //  9,600,000 B

  hipMemsetAsync(cnt, 0, NN * sizeof(int), stream);
  prep_weights<<<(285184 + 255) / 256, 256, 0, stream>>>(we1, we2, wc1, wn1, wn2,
                                                         W1p, W2p, Wc1p, Wn1p, Wn2p);
  prep_nodes<<<(NN * 17 + 255) / 256, 256, 0, stream>>>(x, node_p, coords_p);
  build_adj<<<(NE + 255) / 256, 256, 0, stream>>>(eidx, cnt, adj);
  edge_kernel<<<NE / 32, 256, 0, stream>>>(node_p, coords_p, eidx, W1p, W2p, Wc1p,
                                           be1, be2, bc1, bc2, wc2, medge, coordw);
  node_kernel<<<(NN + 63) / 64, 256, 0, stream>>>(node_p, x, coords_p, medge, coordw,
                                                  eidx, cnt, adj, Wn1p, Wn2p, bn1, bn2,
                                                  (float*)d_out);
}

// Round 6
// 684.047 us; speedup vs baseline: 1.1960x; 1.0061x over previous
//
#include <hip/hip_runtime.h>
#include <hip/hip_bf16.h>

#define NN 50000
#define NE 500000
#define DCAP 48

using bf16x8 = __attribute__((ext_vector_type(8))) short;
using f32x4  = __attribute__((ext_vector_type(4))) float;

__device__ __forceinline__ float b2f(unsigned short s) {
  union { unsigned u; float f; } v; v.u = ((unsigned)s) << 16; return v.f;
}
__device__ __forceinline__ unsigned short f2b(float f) {
  __hip_bfloat16 h = __float2bfloat16(f);
  return *reinterpret_cast<unsigned short*>(&h);
}
// packed 2xf32 -> 2xbf16 (v_cvt_pk path where available)
__device__ __forceinline__ unsigned pack2(float a, float b) {
  __hip_bfloat162 h = __float22bfloat162_rn(make_float2(a, b));
  return *reinterpret_cast<unsigned*>(&h);
}
__device__ __forceinline__ float silu_f(float x) {
  return x * __fdividef(1.f, 1.f + __expf(-x));
}

// ---------------- prep: weight repack f32 -> bf16 (K-major, zero-padded) ----
__global__ void prep_weights(const float* __restrict__ we1,
                             const float* __restrict__ we2,
                             const float* __restrict__ wc1,
                             const float* __restrict__ wn1,
                             const float* __restrict__ wn2,
                             unsigned short* __restrict__ W1p,
                             unsigned short* __restrict__ W2p,
                             unsigned short* __restrict__ Wc1p,
                             unsigned short* __restrict__ Wn1p,
                             unsigned short* __restrict__ Wn2p) {
  int i = blockIdx.x * 256 + threadIdx.x;
  if (i < 152064) {
    int n = i / 288, k = i % 288;
    W1p[i] = (n < 514 && k < 257) ? f2b(we1[k * 514 + n]) : (unsigned short)0;
  } else if (i < 186880) {
    int j = i - 152064; int n = j / 544, k = j % 544;
    W2p[j] = (k < 514) ? f2b(we2[k * 64 + n]) : (unsigned short)0;
  } else if (i < 203264) {
    int j = i - 186880; int n = j / 64, k = j % 64;
    Wc1p[j] = f2b(wc1[k * 256 + n]);
  } else if (i < 252416) {
    int j = i - 203264; int n = j / 192, k = j % 192;
    Wn1p[j] = f2b(wn1[k * 256 + n]);
  } else if (i < 285184) {
    int j = i - 252416; int n = j / 256, k = j % 256;
    Wn2p[j] = f2b(wn2[k * 128 + n]);
  }
}

// x(N,131) f32 -> node_p(N,128) bf16 + coords_p(N,4) f32
__global__ void prep_nodes(const float* __restrict__ x,
                           unsigned short* __restrict__ node_p,
                           float* __restrict__ coords_p) {
  int i = blockIdx.x * 256 + threadIdx.x;
  if (i < NN * 16) {
    int g = i >> 4, c = i & 15;
    const float* s = x + g * 131 + c * 8;
    unsigned short* d = node_p + g * 128 + c * 8;
#pragma unroll
    for (int j = 0; j < 8; j++) d[j] = f2b(s[j]);
  } else if (i < NN * 16 + NN) {
    int g = i - NN * 16;
    float4 c;
    c.x = x[g * 131 + 128];
    c.y = x[g * 131 + 129];
    c.z = x[g * 131 + 130];
    c.w = 0.f;
    *(float4*)(coords_p + g * 4) = c;
  }
}

// CSR-lite: per-dst edge list
__global__ void build_adj(const int* __restrict__ eidx,
                          int* __restrict__ cnt, int* __restrict__ adj) {
  int e = blockIdx.x * 256 + threadIdx.x;
  if (e < NE) {
    int d = eidx[NE + e];
    d = min(max(d, 0), NN - 1);
    int slot = atomicAdd(&cnt[d], 1);
    if (slot < DCAP) adj[d * DCAP + slot] = e;
  }
}

// ------------- edge kernel: 32 edges / block, chunked, D^T orientation ------
// mfma(W_frag, feat_frag, acc): out lane holds edge=l16 (col), 4 consecutive
// n (rows quad*4+r) -> packed ds_write_b64 epilogues, float4 bias loads.
__launch_bounds__(256, 4)
__global__ void edge_kernel(const unsigned short* __restrict__ node_p,
                            const float* __restrict__ coords_p,
                            const int* __restrict__ eidx,
                            const unsigned short* __restrict__ W1p,
                            const unsigned short* __restrict__ W2p,
                            const unsigned short* __restrict__ Wc1p,
                            const float* __restrict__ be1,
                            const float* __restrict__ be2,
                            const float* __restrict__ bc1,
                            const float* __restrict__ bc2,
                            const float* __restrict__ wc2,
                            unsigned short* __restrict__ medge,
                            float* __restrict__ coordw) {
  __shared__ unsigned short sEin[32][296];  // 18,944 B
  __shared__ unsigned short sHc[32][136];   //  8,704 B (one 128-col h chunk)
  __shared__ unsigned short sM[32][72];     //  4,608 B
  __shared__ int sDst[32];
  __shared__ int sSrc[32];
  __shared__ float sCwPart[4][32];
  int tid = threadIdx.x, blk = blockIdx.x;
  int lane = tid & 63, wv = tid >> 6, l16 = lane & 15, quad = lane >> 4;

  // ---- phase 0: per-edge scalars ----
  if (tid < 32) {
    int e = blk * 32 + tid;
    int s = eidx[e], d = eidx[NE + e];
    s = min(max(s, 0), NN - 1);
    d = min(max(d, 0), NN - 1);
    float4 cs = *(const float4*)(coords_p + s * 4);
    float4 cd = *(const float4*)(coords_p + d * 4);
    float rx = cs.x - cd.x, ry = cs.y - cd.y, rz = cs.z - cd.z;
    float dist = sqrtf(rx * rx + ry * ry + rz * rz);
    sDst[tid] = d;
    sSrc[tid] = s;
    sEin[tid][256] = f2b(dist);
#pragma unroll
    for (int k = 257; k < 288; k++) sEin[tid][k] = 0;
  }
  __syncthreads();
  // ---- gather node features: e_in = [node[dst] | node[src] | dist] ----
#pragma unroll
  for (int it = 0; it < 4; it++) {
    int c = tid + it * 256;
    int row = c >> 5, h = (c >> 4) & 1, off = c & 15;
    int id = h ? sSrc[row] : sDst[row];
    bf16x8 v = *(const bf16x8*)(node_p + id * 128 + off * 8);
    *(bf16x8*)(&sEin[row][h * 128 + off * 8]) = v;
  }
  __syncthreads();

  // ---- fused layer1+layer2 over 5 K-chunks (4x128 + 1x32 cols of h) ----
  f32x4 macc[2];
  macc[0] = (f32x4){0.f, 0.f, 0.f, 0.f};
  macc[1] = (f32x4){0.f, 0.f, 0.f, 0.f};
#pragma unroll 1
  for (int ch = 0; ch < 5; ch++) {
    if (ch < 4) {
      f32x4 acc[2][2];
#pragma unroll
      for (int j = 0; j < 2; j++)
#pragma unroll
        for (int s = 0; s < 2; s++) acc[j][s] = (f32x4){0.f, 0.f, 0.f, 0.f};
      for (int kb = 0; kb < 9; kb++) {
        bf16x8 afr[2], bfr[2];
#pragma unroll
        for (int s = 0; s < 2; s++)
          afr[s] = *(const bf16x8*)(&sEin[s * 16 + l16][kb * 32 + quad * 8]);
#pragma unroll
        for (int j = 0; j < 2; j++)
          bfr[j] = *(const bf16x8*)(W1p + ((ch * 8 + wv * 2 + j) * 16 + l16) * 288 + kb * 32 + quad * 8);
#pragma unroll
        for (int j = 0; j < 2; j++)
#pragma unroll
          for (int s = 0; s < 2; s++)
            acc[j][s] = __builtin_amdgcn_mfma_f32_16x16x32_bf16(bfr[j], afr[s], acc[j][s], 0, 0, 0);
      }
#pragma unroll
      for (int j = 0; j < 2; j++) {
        int nb = (ch * 8 + wv * 2 + j) * 16 + quad * 4;   // global n base (mult of 4)
        float4 b4 = *(const float4*)(be1 + nb);           // nb+3 <= 511 < 514
        int lc = (wv * 2 + j) * 16 + quad * 4;
#pragma unroll
        for (int s = 0; s < 2; s++) {
          unsigned lo = pack2(silu_f(acc[j][s][0] + b4.x), silu_f(acc[j][s][1] + b4.y));
          unsigned hi = pack2(silu_f(acc[j][s][2] + b4.z), silu_f(acc[j][s][3] + b4.w));
          *(uint2*)(&sHc[s * 16 + l16][lc]) = make_uint2(lo, hi);
        }
      }
    } else {
      if (wv == 0) {  // tail tile: n = 512 + quad*4 + r (valid only quad==0, r<2)
        f32x4 acc[2];
        acc[0] = (f32x4){0.f, 0.f, 0.f, 0.f};
        acc[1] = (f32x4){0.f, 0.f, 0.f, 0.f};
        for (int kb = 0; kb < 9; kb++) {
          bf16x8 b = *(const bf16x8*)(W1p + (512 + l16) * 288 + kb * 32 + quad * 8);
#pragma unroll
          for (int s = 0; s < 2; s++) {
            bf16x8 a = *(const bf16x8*)(&sEin[s * 16 + l16][kb * 32 + quad * 8]);
            acc[s] = __builtin_amdgcn_mfma_f32_16x16x32_bf16(b, a, acc[s], 0, 0, 0);
          }
        }
        // W1p rows >=514 are zero => acc==0 there; bias 0 => silu(0)=0 pad
        float bq0 = (quad == 0) ? be1[512] : 0.f;
        float bq1 = (quad == 0) ? be1[513] : 0.f;
#pragma unroll
        for (int s = 0; s < 2; s++) {
          unsigned lo = pack2(silu_f(acc[s][0] + bq0), silu_f(acc[s][1] + bq1));
          unsigned hi = pack2(silu_f(acc[s][2]), silu_f(acc[s][3]));
          *(uint2*)(&sHc[s * 16 + l16][quad * 4]) = make_uint2(lo, hi);
        }
      } else if (wv == 1) {  // zero-fill cols 16..31 (pad)
#pragma unroll
        for (int s = 0; s < 2; s++)
          *(uint2*)(&sHc[s * 16 + l16][16 + quad * 4]) = make_uint2(0u, 0u);
      }
    }
    __syncthreads();
    // consume: layer2 partial over this chunk's K
    int nkb = (ch < 4) ? 4 : 1;
    for (int kb = 0; kb < nkb; kb++) {
      bf16x8 b = *(const bf16x8*)(W2p + (wv * 16 + l16) * 544 + ch * 128 + kb * 32 + quad * 8);
#pragma unroll
      for (int s = 0; s < 2; s++) {
        bf16x8 a = *(const bf16x8*)(&sHc[s * 16 + l16][kb * 32 + quad * 8]);
        macc[s] = __builtin_amdgcn_mfma_f32_16x16x32_bf16(b, a, macc[s], 0, 0, 0);
      }
    }
    __syncthreads();
  }

  // ---- layer 2 epilogue: m_ij = silu(. + b_e2) -> sM (packed b64) ----
  {
    int nb = wv * 16 + quad * 4;
    float4 b4 = *(const float4*)(be2 + nb);
#pragma unroll
    for (int s = 0; s < 2; s++) {
      unsigned lo = pack2(silu_f(macc[s][0] + b4.x), silu_f(macc[s][1] + b4.y));
      unsigned hi = pack2(silu_f(macc[s][2] + b4.z), silu_f(macc[s][3] + b4.w));
      *(uint2*)(&sM[s * 16 + l16][nb]) = make_uint2(lo, hi);
    }
  }
  __syncthreads();

  // ---- coord head: cw = silu(m @ W_c1 + b_c1) @ W_c2 ----
  {
    float cw[2] = {0.f, 0.f};
#pragma unroll
    for (int jt = 0; jt < 4; jt++) {
      int T = wv * 4 + jt;
      f32x4 cacc[2];
      cacc[0] = (f32x4){0.f, 0.f, 0.f, 0.f};
      cacc[1] = (f32x4){0.f, 0.f, 0.f, 0.f};
#pragma unroll
      for (int kb = 0; kb < 2; kb++) {
        bf16x8 b = *(const bf16x8*)(Wc1p + (T * 16 + l16) * 64 + kb * 32 + quad * 8);
#pragma unroll
        for (int s = 0; s < 2; s++) {
          bf16x8 a = *(const bf16x8*)(&sM[s * 16 + l16][kb * 32 + quad * 8]);
          cacc[s] = __builtin_amdgcn_mfma_f32_16x16x32_bf16(b, a, cacc[s], 0, 0, 0);
        }
      }
      int nb = T * 16 + quad * 4;
      float4 b4 = *(const float4*)(bc1 + nb);
      float4 w4 = *(const float4*)(wc2 + nb);
#pragma unroll
      for (int s = 0; s < 2; s++) {
        cw[s] += silu_f(cacc[s][0] + b4.x) * w4.x;
        cw[s] += silu_f(cacc[s][1] + b4.y) * w4.y;
        cw[s] += silu_f(cacc[s][2] + b4.z) * w4.z;
        cw[s] += silu_f(cacc[s][3] + b4.w) * w4.w;
      }
    }
    // reduce over quads (lanes sharing l16)
#pragma unroll
    for (int s = 0; s < 2; s++) {
      cw[s] += __shfl_xor(cw[s], 16, 64);
      cw[s] += __shfl_xor(cw[s], 32, 64);
    }
    if (quad == 0) {
#pragma unroll
      for (int s = 0; s < 2; s++) sCwPart[wv][s * 16 + l16] = cw[s];
    }
  }
  __syncthreads();
  // ---- coalesced stores: m_ij rows (16B/lane) + coord_w scalar ----
  {
    int row = tid >> 3, ch = tid & 7;
    int e = blk * 32 + row;
    *(bf16x8*)(medge + (size_t)e * 64 + ch * 8) = *(const bf16x8*)(&sM[row][ch * 8]);
  }
  if (tid < 32) {
    float v = sCwPart[0][tid] + sCwPart[1][tid] + sCwPart[2][tid] + sCwPart[3][tid]
              + bc2[0];
    coordw[blk * 32 + tid] = v;
  }
}

// ---------------- node kernel: gather-reduce + MLP, f32 output -------------
__launch_bounds__(256, 2)
__global__ void node_kernel(const unsigned short* __restrict__ node_p,
                            const float* __restrict__ x,
                            const float* __restrict__ coords_p,
                            const unsigned short* __restrict__ medge,
                            const float* __restrict__ coordw,
                            const int* __restrict__ eidx,
                            const int* __restrict__ cnt,
                            const int* __restrict__ adj,
                            const unsigned short* __restrict__ Wn1p,
                            const unsigned short* __restrict__ Wn2p,
                            const float* __restrict__ bn1,
                            const float* __restrict__ bn2,
                            float* __restrict__ out) {
  __shared__ unsigned short sNin[64][200];
  __shared__ unsigned short sHid[64][264];
  __shared__ float sWR[64][4];   // [rx, ry, rz, w] per node
  int tid = threadIdx.x, blk = blockIdx.x;
  int lane = tid & 63, wv = tid >> 6, l16 = lane & 15, quad = lane >> 4;

  // ---- phase A: gather-reduce m_i (f32), r_i, w_i — no atomics ----
  {
    int j = tid >> 2, c = tid & 3;
    int g = blk * 64 + j;
    int gc = min(g, NN - 1);
    int deg = min(cnt[gc], DCAP);
    if (g >= NN) deg = 0;
    float acc[16];
#pragma unroll
    for (int i = 0; i < 16; i++) acc[i] = 0.f;
    float sc = 0.f;
    float cg = (c < 3) ? coords_p[gc * 4 + c] : 0.f;
    for (int k = 0; k < deg; k++) {
      int e = adj[gc * DCAP + k];
      const unsigned short* mrow = medge + (size_t)e * 64 + c * 16;
      bf16x8 a0 = *(const bf16x8*)(mrow);
      bf16x8 a1 = *(const bf16x8*)(mrow + 8);
#pragma unroll
      for (int i = 0; i < 8; i++) acc[i] += b2f((unsigned short)a0[i]);
#pragma unroll
      for (int i = 0; i < 8; i++) acc[8 + i] += b2f((unsigned short)a1[i]);
      if (c == 3) {
        sc += coordw[e];
      } else {
        int s = eidx[e];
        s = min(max(s, 0), NN - 1);
        sc += coords_p[s * 4 + c] - cg;
      }
    }
#pragma unroll
    for (int i = 0; i < 16; i += 2)
      *(unsigned*)(&sNin[j][128 + c * 16 + i]) = pack2(acc[i], acc[i + 1]);
    sWR[j][c] = sc;
  }
  // ---- stage node features ----
#pragma unroll
  for (int it = 0; it < 4; it++) {
    int t = tid + it * 256;
    int row = t >> 4, ch = t & 15;
    int g = blk * 64 + row;
    if (g >= NN) g = 0;
    *(bf16x8*)(&sNin[row][ch * 8]) = *(const bf16x8*)(node_p + g * 128 + ch * 8);
  }
  __syncthreads();
  // ---- GEMM1: hid = silu(n_in @ W_n1 + b_n1), D^T orientation ----
  {
    f32x4 acc[4][4];
#pragma unroll
    for (int j = 0; j < 4; j++)
#pragma unroll
      for (int s = 0; s < 4; s++) acc[j][s] = (f32x4){0.f, 0.f, 0.f, 0.f};
    for (int kb = 0; kb < 6; kb++) {
      bf16x8 afr[4], bfr[4];
#pragma unroll
      for (int s = 0; s < 4; s++)
        afr[s] = *(const bf16x8*)(&sNin[s * 16 + l16][kb * 32 + quad * 8]);
#pragma unroll
      for (int j = 0; j < 4; j++)
        bfr[j] = *(const bf16x8*)(Wn1p + ((wv * 4 + j) * 16 + l16) * 192 + kb * 32 + quad * 8);
#pragma unroll
      for (int j = 0; j < 4; j++)
#pragma unroll
        for (int s = 0; s < 4; s++)
          acc[j][s] = __builtin_amdgcn_mfma_f32_16x16x32_bf16(bfr[j], afr[s], acc[j][s], 0, 0, 0);
    }
#pragma unroll
    for (int j = 0; j < 4; j++) {
      int nb = (wv * 4 + j) * 16 + quad * 4;
      float4 b4 = *(const float4*)(bn1 + nb);
#pragma unroll
      for (int s = 0; s < 4; s++) {
        unsigned lo = pack2(silu_f(acc[j][s][0] + b4.x), silu_f(acc[j][s][1] + b4.y));
        unsigned hi = pack2(silu_f(acc[j][s][2] + b4.z), silu_f(acc[j][s][3] + b4.w));
        *(uint2*)(&sHid[s * 16 + l16][nb]) = make_uint2(lo, hi);
      }
    }
  }
  __syncthreads();
  // ---- GEMM2: out = hid @ W_n2 + b_n2 + node (f32 residual from x) ----
  {
    f32x4 acc[2][4];
#pragma unroll
    for (int j = 0; j < 2; j++)
#pragma unroll
      for (int s = 0; s < 4; s++) acc[j][s] = (f32x4){0.f, 0.f, 0.f, 0.f};
    for (int kb = 0; kb < 8; kb++) {
      bf16x8 afr[4], bfr[2];
#pragma unroll
      for (int s = 0; s < 4; s++)
        afr[s] = *(const bf16x8*)(&sHid[s * 16 + l16][kb * 32 + quad * 8]);
#pragma unroll
      for (int j = 0; j < 2; j++)
        bfr[j] = *(const bf16x8*)(Wn2p + ((wv * 2 + j) * 16 + l16) * 256 + kb * 32 + quad * 8);
#pragma unroll
      for (int j = 0; j < 2; j++)
#pragma unroll
        for (int s = 0; s < 4; s++)
          acc[j][s] = __builtin_amdgcn_mfma_f32_16x16x32_bf16(bfr[j], afr[s], acc[j][s], 0, 0, 0);
    }
#pragma unroll
    for (int j = 0; j < 2; j++) {
      int nb = (wv * 2 + j) * 16 + quad * 4;
      float4 b4 = *(const float4*)(bn2 + nb);
#pragma unroll
      for (int s = 0; s < 4; s++) {
        int g = blk * 64 + s * 16 + l16;
        if (g < NN) {
          int base = g * 131 + nb;
          out[base + 0] = acc[j][s][0] + b4.x + x[base + 0];
          out[base + 1] = acc[j][s][1] + b4.y + x[base + 1];
          out[base + 2] = acc[j][s][2] + b4.z + x[base + 2];
          out[base + 3] = acc[j][s][3] + b4.w + x[base + 3];
        }
      }
    }
  }
  // ---- coords_out = coords + w_i * r_i ----
  if (tid < 64) {
    int g = blk * 64 + tid;
    if (g < NN) {
      float w = sWR[tid][3];
      out[g * 131 + 128] = coords_p[g * 4 + 0] + w * sWR[tid][0];
      out[g * 131 + 129] = coords_p[g * 4 + 1] + w * sWR[tid][1];
      out[g * 131 + 130] = coords_p[g * 4 + 2] + w * sWR[tid][2];
    }
  }
}

extern "C" void kernel_launch(void* const* d_in, const int* in_sizes, int n_in,
                              void* d_out, int out_size, void* d_ws, size_t ws_size,
                              hipStream_t stream) {
  const float* x   = (const float*)d_in[0];
  const int* eidx  = (const int*)d_in[1];
  const float* we1 = (const float*)d_in[2];
  const float* be1 = (const float*)d_in[3];
  const float* we2 = (const float*)d_in[4];
  const float* be2 = (const float*)d_in[5];
  const float* wc1 = (const float*)d_in[6];
  const float* bc1 = (const float*)d_in[7];
  const float* wc2 = (const float*)d_in[8];
  const float* bc2 = (const float*)d_in[9];
  const float* wn1 = (const float*)d_in[10];
  const float* bn1 = (const float*)d_in[11];
  const float* wn2 = (const float*)d_in[12];
  const float* bn2 = (const float*)d_in[13];

  char* ws = (char*)d_ws;
  unsigned short* W1p    = (unsigned short*)(ws + 0);          //    304,128 B
  unsigned short* W2p    = (unsigned short*)(ws + 304128);     //     69,632 B
  unsigned short* Wc1p   = (unsigned short*)(ws + 373760);     //     32,768 B
  unsigned short* Wn1p   = (unsigned short*)(ws + 406528);     //     98,304 B
  unsigned short* Wn2p   = (unsigned short*)(ws + 504832);     //     65,536 B
  unsigned short* node_p = (unsigned short*)(ws + 570368);     // 12,800,000 B
  float* coords_p        = (float*)(ws + 13370368);            //    800,000 B
  unsigned short* medge  = (unsigned short*)(ws + 14170368);   // 64,000,000 B
  float* coordw          = (float*)(ws + 78170368);            //  2,000,000 B
  int* cnt               = (int*)(ws + 80170368);              //    200,000 B
  int* adj               = (int*)(ws + 80370368);              //  9,600,000 B

  hipMemsetAsync(cnt, 0, NN * sizeof(int), stream);
  prep_weights<<<(285184 + 255) / 256, 256, 0, stream>>>(we1, we2, wc1, wn1, wn2,
                                                         W1p, W2p, Wc1p, Wn1p, Wn2p);
  prep_nodes<<<(NN * 17 + 255) / 256, 256, 0, stream>>>(x, node_p, coords_p);
  build_adj<<<(NE + 255) / 256, 256, 0, stream>>>(eidx, cnt, adj);
  edge_kernel<<<NE / 32, 256, 0, stream>>>(node_p, coords_p, eidx, W1p, W2p, Wc1p,
                                           be1, be2, bc1, bc2, wc2, medge, coordw);
  node_kernel<<<(NN + 63) / 64, 256, 0, stream>>>(node_p, x, coords_p, medge, coordw,
                                                  eidx, cnt, adj, Wn1p, Wn2p, bn1, bn2,
                                                  (float*)d_out);
}

// Round 7
// 633.548 us; speedup vs baseline: 1.2913x; 1.0797x over previous
//
#include <hip/hip_runtime.h>
#include <hip/hip_bf16.h>

#define NN 50000
#define NE 500000
#define DCAP 48

using bf16x8 = __attribute__((ext_vector_type(8))) short;
using f32x4  = __attribute__((ext_vector_type(4))) float;

__device__ __forceinline__ float b2f(unsigned short s) {
  union { unsigned u; float f; } v; v.u = ((unsigned)s) << 16; return v.f;
}
__device__ __forceinline__ unsigned short f2b(float f) {
  __hip_bfloat16 h = __float2bfloat16(f);
  return *reinterpret_cast<unsigned short*>(&h);
}
__device__ __forceinline__ unsigned pack2(float a, float b) {
  __hip_bfloat162 h = __float22bfloat162_rn(make_float2(a, b));
  return *reinterpret_cast<unsigned*>(&h);
}
__device__ __forceinline__ float silu_f(float x) {
  return x * __fdividef(1.f, 1.f + __expf(-x));
}

// ---------------- prep: weight repack f32 -> bf16 ----------------
// W1p[528][288]: k<257 = W_e1, k==257 = b_e1 (bias-one trick), else 0
// W2p[64][544]:  K-permuted: lk<128 -> h[lk]; lk 128,129 -> h[512,513];
//                lk==130 -> b_e2; lk 131..159 -> 0; lk>=160 -> h[lk-32]
// Wc1p[256][64], Wn1p[256][192], Wn2p[128][256]: straight K-major
__global__ void prep_weights(const float* __restrict__ we1,
                             const float* __restrict__ be1,
                             const float* __restrict__ we2,
                             const float* __restrict__ be2,
                             const float* __restrict__ wc1,
                             const float* __restrict__ wn1,
                             const float* __restrict__ wn2,
                             unsigned short* __restrict__ W1p,
                             unsigned short* __restrict__ W2p,
                             unsigned short* __restrict__ Wc1p,
                             unsigned short* __restrict__ Wn1p,
                             unsigned short* __restrict__ Wn2p) {
  int i = blockIdx.x * 256 + threadIdx.x;
  if (i < 152064) {
    int n = i / 288, k = i % 288;
    unsigned short v = 0;
    if (n < 514) {
      if (k < 257) v = f2b(we1[k * 514 + n]);
      else if (k == 257) v = f2b(be1[n]);
    }
    W1p[i] = v;
  } else if (i < 186880) {
    int j = i - 152064; int n = j / 544, lk = j % 544;
    unsigned short v = 0;
    if (lk < 128) v = f2b(we2[lk * 64 + n]);
    else if (lk < 130) v = f2b(we2[(512 + lk - 128) * 64 + n]);
    else if (lk == 130) v = f2b(be2[n]);
    else if (lk >= 160) v = f2b(we2[(lk - 32) * 64 + n]);
    W2p[j] = v;
  } else if (i < 203264) {
    int j = i - 186880; int n = j / 64, k = j % 64;
    Wc1p[j] = f2b(wc1[k * 256 + n]);
  } else if (i < 252416) {
    int j = i - 203264; int n = j / 192, k = j % 192;
    Wn1p[j] = f2b(wn1[k * 256 + n]);
  } else if (i < 285184) {
    int j = i - 252416; int n = j / 256, k = j % 256;
    Wn2p[j] = f2b(wn2[k * 128 + n]);
  }
}

// x(N,131) f32 -> node_p(N,128) bf16 + coords_p(N,4) f32
__global__ void prep_nodes(const float* __restrict__ x,
                           unsigned short* __restrict__ node_p,
                           float* __restrict__ coords_p) {
  int i = blockIdx.x * 256 + threadIdx.x;
  if (i < NN * 16) {
    int g = i >> 4, c = i & 15;
    const float* s = x + g * 131 + c * 8;
    unsigned short* d = node_p + g * 128 + c * 8;
#pragma unroll
    for (int j = 0; j < 8; j++) d[j] = f2b(s[j]);
  } else if (i < NN * 16 + NN) {
    int g = i - NN * 16;
    float4 c;
    c.x = x[g * 131 + 128];
    c.y = x[g * 131 + 129];
    c.z = x[g * 131 + 130];
    c.w = 0.f;
    *(float4*)(coords_p + g * 4) = c;
  }
}

// CSR-lite: per-dst edge list
__global__ void build_adj(const int* __restrict__ eidx,
                          int* __restrict__ cnt, int* __restrict__ adj) {
  int e = blockIdx.x * 256 + threadIdx.x;
  if (e < NE) {
    int d = eidx[NE + e];
    d = min(max(d, 0), NN - 1);
    int slot = atomicAdd(&cnt[d], 1);
    if (slot < DCAP) adj[d * DCAP + slot] = e;
  }
}

// ------------- edge kernel: 64 edges / block, 4 chunks, biases in GEMM ------
// sEin stride 328 (164 dw = 4 mod 32: conflict-free b128), sHc 200, sM 72.
// LDS 78.3 KB -> 2 blocks/CU. D^T orientation (mfma(W, feat)).
__launch_bounds__(256, 2)
__global__ void edge_kernel(const unsigned short* __restrict__ node_p,
                            const float* __restrict__ coords_p,
                            const int* __restrict__ eidx,
                            const unsigned short* __restrict__ W1p,
                            const unsigned short* __restrict__ W2p,
                            const unsigned short* __restrict__ Wc1p,
                            const float* __restrict__ bc1,
                            const float* __restrict__ bc2,
                            const float* __restrict__ wc2,
                            unsigned short* __restrict__ medge,
                            float* __restrict__ coordw) {
  __shared__ unsigned short sEin[64][328];  // 41,984 B
  __shared__ unsigned short sHc[64][200];   // 25,600 B (160-col chunk0 / 128 after)
  __shared__ unsigned short sM[64][72];     //  9,216 B
  __shared__ int sDst[64];
  __shared__ int sSrc[64];
  __shared__ float sCwPart[4][64];
  int tid = threadIdx.x, blk = blockIdx.x;
  int lane = tid & 63, wv = tid >> 6, l16 = lane & 15, quad = lane >> 4;

  // ---- phase 0: per-edge scalars (bias-one at k=257) ----
  if (tid < 64) {
    int e = min(blk * 64 + tid, NE - 1);
    int s = eidx[e], d = eidx[NE + e];
    s = min(max(s, 0), NN - 1);
    d = min(max(d, 0), NN - 1);
    float4 cs = *(const float4*)(coords_p + s * 4);
    float4 cd = *(const float4*)(coords_p + d * 4);
    float rx = cs.x - cd.x, ry = cs.y - cd.y, rz = cs.z - cd.z;
    float dist = sqrtf(rx * rx + ry * ry + rz * rz);
    sDst[tid] = d;
    sSrc[tid] = s;
    sEin[tid][256] = f2b(dist);
    sEin[tid][257] = 0x3F80;  // 1.0 bf16 -> bias row of W1p
#pragma unroll
    for (int k = 258; k < 288; k += 2) *(unsigned*)(&sEin[tid][k]) = 0u;
  }
  __syncthreads();
  // ---- gather node features: e_in = [node[dst] | node[src] | dist | 1] ----
#pragma unroll
  for (int it = 0; it < 8; it++) {
    int c = tid + it * 256;
    int row = c >> 5, h = (c >> 4) & 1, off = c & 15;
    int id = h ? sSrc[row] : sDst[row];
    bf16x8 v = *(const bf16x8*)(node_p + id * 128 + off * 8);
    *(bf16x8*)(&sEin[row][h * 128 + off * 8]) = v;
  }
  __syncthreads();

  // ---- fused layer1+layer2 over 4 chunks (ch0: 160 cols incl. tail+bias) ----
  f32x4 macc[4];
#pragma unroll
  for (int s = 0; s < 4; s++) macc[s] = (f32x4){0.f, 0.f, 0.f, 0.f};
#pragma unroll 1
  for (int ch = 0; ch < 4; ch++) {
    {  // produce 2 n-tiles per wave (128 cols)
      f32x4 acc[2][4];
#pragma unroll
      for (int j = 0; j < 2; j++)
#pragma unroll
        for (int s = 0; s < 4; s++) acc[j][s] = (f32x4){0.f, 0.f, 0.f, 0.f};
      for (int kb = 0; kb < 9; kb++) {
        bf16x8 afr[4], bfr[2];
#pragma unroll
        for (int s = 0; s < 4; s++)
          afr[s] = *(const bf16x8*)(&sEin[s * 16 + l16][kb * 32 + quad * 8]);
#pragma unroll
        for (int j = 0; j < 2; j++)
          bfr[j] = *(const bf16x8*)(W1p + ((ch * 8 + wv * 2 + j) * 16 + l16) * 288 + kb * 32 + quad * 8);
#pragma unroll
        for (int j = 0; j < 2; j++)
#pragma unroll
          for (int s = 0; s < 4; s++)
            acc[j][s] = __builtin_amdgcn_mfma_f32_16x16x32_bf16(bfr[j], afr[s], acc[j][s], 0, 0, 0);
      }
#pragma unroll
      for (int j = 0; j < 2; j++) {
        int lc = (wv * 2 + j) * 16 + quad * 4;
#pragma unroll
        for (int s = 0; s < 4; s++) {
          unsigned lo = pack2(silu_f(acc[j][s][0]), silu_f(acc[j][s][1]));
          unsigned hi = pack2(silu_f(acc[j][s][2]), silu_f(acc[j][s][3]));
          *(uint2*)(&sHc[s * 16 + l16][lc]) = make_uint2(lo, hi);
        }
      }
    }
    if (ch == 0) {  // tail tile (n=512..527): wave wv handles subtile s=wv
      f32x4 tacc = (f32x4){0.f, 0.f, 0.f, 0.f};
      for (int kb = 0; kb < 9; kb++) {
        bf16x8 b = *(const bf16x8*)(W1p + (512 + l16) * 288 + kb * 32 + quad * 8);
        bf16x8 a = *(const bf16x8*)(&sEin[wv * 16 + l16][kb * 32 + quad * 8]);
        tacc = __builtin_amdgcn_mfma_f32_16x16x32_bf16(b, a, tacc, 0, 0, 0);
      }
      // local cols 128..130 = h[512], h[513], bias-one; 131..159 = 0
      unsigned lo, hi;
      if (quad == 0) {
        lo = pack2(silu_f(tacc[0]), silu_f(tacc[1]));
        hi = pack2(1.0f, 0.f);
      } else {
        lo = 0u; hi = 0u;
      }
      *(uint2*)(&sHc[wv * 16 + l16][128 + quad * 4]) = make_uint2(lo, hi);
      *(uint2*)(&sHc[wv * 16 + l16][144 + quad * 4]) = make_uint2(0u, 0u);
    }
    __syncthreads();
    // consume: layer2 partial (bias already in W2p k-permuted layout)
    int nkb = (ch == 0) ? 5 : 4;
    int kof = (ch == 0) ? 0 : (32 + 128 * ch);
    for (int kb = 0; kb < nkb; kb++) {
      bf16x8 b = *(const bf16x8*)(W2p + (wv * 16 + l16) * 544 + kof + kb * 32 + quad * 8);
#pragma unroll
      for (int s = 0; s < 4; s++) {
        bf16x8 a = *(const bf16x8*)(&sHc[s * 16 + l16][kb * 32 + quad * 8]);
        macc[s] = __builtin_amdgcn_mfma_f32_16x16x32_bf16(b, a, macc[s], 0, 0, 0);
      }
    }
    __syncthreads();
  }

  // ---- layer 2 epilogue: m_ij = silu(macc) -> sM (packed b64) ----
  {
    int nb = wv * 16 + quad * 4;
#pragma unroll
    for (int s = 0; s < 4; s++) {
      unsigned lo = pack2(silu_f(macc[s][0]), silu_f(macc[s][1]));
      unsigned hi = pack2(silu_f(macc[s][2]), silu_f(macc[s][3]));
      *(uint2*)(&sM[s * 16 + l16][nb]) = make_uint2(lo, hi);
    }
  }
  __syncthreads();

  // ---- coord head: cw = silu(m @ W_c1 + b_c1) @ W_c2 ----
  {
    float cw[4] = {0.f, 0.f, 0.f, 0.f};
#pragma unroll
    for (int jt = 0; jt < 4; jt++) {
      int T = wv * 4 + jt;
      f32x4 cacc[4];
#pragma unroll
      for (int s = 0; s < 4; s++) cacc[s] = (f32x4){0.f, 0.f, 0.f, 0.f};
#pragma unroll
      for (int kb = 0; kb < 2; kb++) {
        bf16x8 b = *(const bf16x8*)(Wc1p + (T * 16 + l16) * 64 + kb * 32 + quad * 8);
#pragma unroll
        for (int s = 0; s < 4; s++) {
          bf16x8 a = *(const bf16x8*)(&sM[s * 16 + l16][kb * 32 + quad * 8]);
          cacc[s] = __builtin_amdgcn_mfma_f32_16x16x32_bf16(b, a, cacc[s], 0, 0, 0);
        }
      }
      int nb = T * 16 + quad * 4;
      float4 b4 = *(const float4*)(bc1 + nb);
      float4 w4 = *(const float4*)(wc2 + nb);
#pragma unroll
      for (int s = 0; s < 4; s++) {
        cw[s] += silu_f(cacc[s][0] + b4.x) * w4.x;
        cw[s] += silu_f(cacc[s][1] + b4.y) * w4.y;
        cw[s] += silu_f(cacc[s][2] + b4.z) * w4.z;
        cw[s] += silu_f(cacc[s][3] + b4.w) * w4.w;
      }
    }
#pragma unroll
    for (int s = 0; s < 4; s++) {
      cw[s] += __shfl_xor(cw[s], 16, 64);
      cw[s] += __shfl_xor(cw[s], 32, 64);
    }
    if (quad == 0) {
#pragma unroll
      for (int s = 0; s < 4; s++) sCwPart[wv][s * 16 + l16] = cw[s];
    }
  }
  __syncthreads();
  // ---- stores: m_ij rows (16B/lane) + coord_w scalar ----
#pragma unroll
  for (int it = 0; it < 2; it++) {
    int idx = it * 256 + tid;
    int row = idx >> 3, ch8 = idx & 7;
    int e = blk * 64 + row;
    if (e < NE)
      *(bf16x8*)(medge + (size_t)e * 64 + ch8 * 8) = *(const bf16x8*)(&sM[row][ch8 * 8]);
  }
  if (tid < 64) {
    int e = blk * 64 + tid;
    if (e < NE) {
      float v = sCwPart[0][tid] + sCwPart[1][tid] + sCwPart[2][tid] + sCwPart[3][tid]
                + bc2[0];
      coordw[e] = v;
    }
  }
}

// ---------------- node kernel: gather-reduce + MLP, f32 output -------------
__launch_bounds__(256, 2)
__global__ void node_kernel(const unsigned short* __restrict__ node_p,
                            const float* __restrict__ x,
                            const float* __restrict__ coords_p,
                            const unsigned short* __restrict__ medge,
                            const float* __restrict__ coordw,
                            const int* __restrict__ eidx,
                            const int* __restrict__ cnt,
                            const int* __restrict__ adj,
                            const unsigned short* __restrict__ Wn1p,
                            const unsigned short* __restrict__ Wn2p,
                            const float* __restrict__ bn1,
                            const float* __restrict__ bn2,
                            float* __restrict__ out) {
  __shared__ unsigned short sNin[64][200];
  __shared__ unsigned short sHid[64][264];
  __shared__ float sWR[64][4];
  int tid = threadIdx.x, blk = blockIdx.x;
  int lane = tid & 63, wv = tid >> 6, l16 = lane & 15, quad = lane >> 4;

  // ---- phase A: gather-reduce m_i (f32), r_i, w_i — no atomics ----
  {
    int j = tid >> 2, c = tid & 3;
    int g = blk * 64 + j;
    int gc = min(g, NN - 1);
    int deg = min(cnt[gc], DCAP);
    if (g >= NN) deg = 0;
    float acc[16];
#pragma unroll
    for (int i = 0; i < 16; i++) acc[i] = 0.f;
    float sc = 0.f;
    float cg = (c < 3) ? coords_p[gc * 4 + c] : 0.f;
    for (int k = 0; k < deg; k++) {
      int e = adj[gc * DCAP + k];
      const unsigned short* mrow = medge + (size_t)e * 64 + c * 16;
      bf16x8 a0 = *(const bf16x8*)(mrow);
      bf16x8 a1 = *(const bf16x8*)(mrow + 8);
#pragma unroll
      for (int i = 0; i < 8; i++) acc[i] += b2f((unsigned short)a0[i]);
#pragma unroll
      for (int i = 0; i < 8; i++) acc[8 + i] += b2f((unsigned short)a1[i]);
      if (c == 3) {
        sc += coordw[e];
      } else {
        int s = eidx[e];
        s = min(max(s, 0), NN - 1);
        sc += coords_p[s * 4 + c] - cg;
      }
    }
#pragma unroll
    for (int i = 0; i < 16; i += 2)
      *(unsigned*)(&sNin[j][128 + c * 16 + i]) = pack2(acc[i], acc[i + 1]);
    sWR[j][c] = sc;
  }
#pragma unroll
  for (int it = 0; it < 4; it++) {
    int t = tid + it * 256;
    int row = t >> 4, ch = t & 15;
    int g = blk * 64 + row;
    if (g >= NN) g = 0;
    *(bf16x8*)(&sNin[row][ch * 8]) = *(const bf16x8*)(node_p + g * 128 + ch * 8);
  }
  __syncthreads();
  // ---- GEMM1: hid = silu(n_in @ W_n1 + b_n1), D^T orientation ----
  {
    f32x4 acc[4][4];
#pragma unroll
    for (int j = 0; j < 4; j++)
#pragma unroll
      for (int s = 0; s < 4; s++) acc[j][s] = (f32x4){0.f, 0.f, 0.f, 0.f};
    for (int kb = 0; kb < 6; kb++) {
      bf16x8 afr[4], bfr[4];
#pragma unroll
      for (int s = 0; s < 4; s++)
        afr[s] = *(const bf16x8*)(&sNin[s * 16 + l16][kb * 32 + quad * 8]);
#pragma unroll
      for (int j = 0; j < 4; j++)
        bfr[j] = *(const bf16x8*)(Wn1p + ((wv * 4 + j) * 16 + l16) * 192 + kb * 32 + quad * 8);
#pragma unroll
      for (int j = 0; j < 4; j++)
#pragma unroll
        for (int s = 0; s < 4; s++)
          acc[j][s] = __builtin_amdgcn_mfma_f32_16x16x32_bf16(bfr[j], afr[s], acc[j][s], 0, 0, 0);
    }
#pragma unroll
    for (int j = 0; j < 4; j++) {
      int nb = (wv * 4 + j) * 16 + quad * 4;
      float4 b4 = *(const float4*)(bn1 + nb);
#pragma unroll
      for (int s = 0; s < 4; s++) {
        unsigned lo = pack2(silu_f(acc[j][s][0] + b4.x), silu_f(acc[j][s][1] + b4.y));
        unsigned hi = pack2(silu_f(acc[j][s][2] + b4.z), silu_f(acc[j][s][3] + b4.w));
        *(uint2*)(&sHid[s * 16 + l16][nb]) = make_uint2(lo, hi);
      }
    }
  }
  __syncthreads();
  // ---- GEMM2: out = hid @ W_n2 + b_n2 + node (f32 residual from x) ----
  {
    f32x4 acc[2][4];
#pragma unroll
    for (int j = 0; j < 2; j++)
#pragma unroll
      for (int s = 0; s < 4; s++) acc[j][s] = (f32x4){0.f, 0.f, 0.f, 0.f};
    for (int kb = 0; kb < 8; kb++) {
      bf16x8 afr[4], bfr[2];
#pragma unroll
      for (int s = 0; s < 4; s++)
        afr[s] = *(const bf16x8*)(&sHid[s * 16 + l16][kb * 32 + quad * 8]);
#pragma unroll
      for (int j = 0; j < 2; j++)
        bfr[j] = *(const bf16x8*)(Wn2p + ((wv * 2 + j) * 16 + l16) * 256 + kb * 32 + quad * 8);
#pragma unroll
      for (int j = 0; j < 2; j++)
#pragma unroll
        for (int s = 0; s < 4; s++)
          acc[j][s] = __builtin_amdgcn_mfma_f32_16x16x32_bf16(bfr[j], afr[s], acc[j][s], 0, 0, 0);
    }
#pragma unroll
    for (int j = 0; j < 2; j++) {
      int nb = (wv * 2 + j) * 16 + quad * 4;
      float4 b4 = *(const float4*)(bn2 + nb);
#pragma unroll
      for (int s = 0; s < 4; s++) {
        int g = blk * 64 + s * 16 + l16;
        if (g < NN) {
          int base = g * 131 + nb;
          out[base + 0] = acc[j][s][0] + b4.x + x[base + 0];
          out[base + 1] = acc[j][s][1] + b4.y + x[base + 1];
          out[base + 2] = acc[j][s][2] + b4.z + x[base + 2];
          out[base + 3] = acc[j][s][3] + b4.w + x[base + 3];
        }
      }
    }
  }
  // ---- coords_out = coords + w_i * r_i ----
  if (tid < 64) {
    int g = blk * 64 + tid;
    if (g < NN) {
      float w = sWR[tid][3];
      out[g * 131 + 128] = coords_p[g * 4 + 0] + w * sWR[tid][0];
      out[g * 131 + 129] = coords_p[g * 4 + 1] + w * sWR[tid][1];
      out[g * 131 + 130] = coords_p[g * 4 + 2] + w * sWR[tid][2];
    }
  }
}

extern "C" void kernel_launch(void* const* d_in, const int* in_sizes, int n_in,
                              void* d_out, int out_size, void* d_ws, size_t ws_size,
                              hipStream_t stream) {
  const float* x   = (const float*)d_in[0];
  const int* eidx  = (const int*)d_in[1];
  const float* we1 = (const float*)d_in[2];
  const float* be1 = (const float*)d_in[3];
  const float* we2 = (const float*)d_in[4];
  const float* be2 = (const float*)d_in[5];
  const float* wc1 = (const float*)d_in[6];
  const float* bc1 = (const float*)d_in[7];
  const float* wc2 = (const float*)d_in[8];
  const float* bc2 = (const float*)d_in[9];
  const float* wn1 = (const float*)d_in[10];
  const float* bn1 = (const float*)d_in[11];
  const float* wn2 = (const float*)d_in[12];
  const float* bn2 = (const float*)d_in[13];

  char* ws = (char*)d_ws;
  unsigned short* W1p    = (unsigned short*)(ws + 0);          //    304,128 B
  unsigned short* W2p    = (unsigned short*)(ws + 304128);     //     69,632 B
  unsigned short* Wc1p   = (unsigned short*)(ws + 373760);     //     32,768 B
  unsigned short* Wn1p   = (unsigned short*)(ws + 406528);     //     98,304 B
  unsigned short* Wn2p   = (unsigned short*)(ws + 504832);     //     65,536 B
  unsigned short* node_p = (unsigned short*)(ws + 570368);     // 12,800,000 B
  float* coords_p        = (float*)(ws + 13370368);            //    800,000 B
  unsigned short* medge  = (unsigned short*)(ws + 14170368);   // 64,000,000 B
  float* coordw          = (float*)(ws + 78170368);            //  2,000,000 B
  int* cnt               = (int*)(ws + 80170368);              //    200,000 B
  int* adj               = (int*)(ws + 80370368);              //  9,600,000 B

  hipMemsetAsync(cnt, 0, NN * sizeof(int), stream);
  prep_weights<<<(285184 + 255) / 256, 256, 0, stream>>>(we1, be1, we2, be2, wc1,
                                                         wn1, wn2, W1p, W2p, Wc1p,
                                                         Wn1p, Wn2p);
  prep_nodes<<<(NN * 17 + 255) / 256, 256, 0, stream>>>(x, node_p, coords_p);
  build_adj<<<(NE + 255) / 256, 256, 0, stream>>>(eidx, cnt, adj);
  edge_kernel<<<(NE + 63) / 64, 256, 0, stream>>>(node_p, coords_p, eidx, W1p, W2p,
                                                  Wc1p, bc1, bc2, wc2, medge, coordw);
  node_kernel<<<(NN + 63) / 64, 256, 0, stream>>>(node_p, x, coords_p, medge, coordw,
                                                  eidx, cnt, adj, Wn1p, Wn2p, bn1, bn2,
                                                  (float*)d_out);
}